// Round 5
// baseline (425.021 us; speedup 1.0000x reference)
//
#include <hip/hip_runtime.h>
#include <hip/hip_bf16.h>
#include <math.h>

#define BB 8
#define CCH 256
#define HWN 4096
#define RR 16

typedef __attribute__((ext_vector_type(8))) short short8;   // 8 bf16 = K=32 MFMA A/B frag (4 VGPRs)
typedef __attribute__((ext_vector_type(4))) float f32x4;    // MFMA C/D frag

static __device__ __forceinline__ unsigned short f2bf(float x) {
    union { float f; unsigned u; } v; v.f = x;
    return (unsigned short)((v.u + 0x8000u) >> 16);   // round-half-up bf16
}

// ---------------- K1: avg+max pool per (b,c); blocks 0..287 also pack Wb (fused wprep) ----
__global__ __launch_bounds__(256) void k_pool(const float* __restrict__ x,
                                              float* __restrict__ avgp,
                                              float* __restrict__ maxp,
                                              const float* __restrict__ vw,
                                              const float* __restrict__ qw,
                                              const float* __restrict__ kw,
                                              unsigned short* __restrict__ Wb) {
    int bc = blockIdx.x;
    int t = threadIdx.x;
    if (bc < 288) {
        int idx = bc * 256 + t;
        int m = idx >> 8, c = idx & 255;
        float v;
        if (m < 256) v = vw[idx];
        else if (m < 272) v = qw[(m - 256) * 256 + c];
        else v = kw[(m - 272) * 256 + c];
        Wb[idx] = f2bf(v);
    }
    const float4* p = (const float4*)(x + (size_t)bc * HWN);
    float s = 0.f, m = -INFINITY;
#pragma unroll
    for (int i = 0; i < 4; ++i) {
        float4 v = p[t + 256 * i];
        s += v.x + v.y + v.z + v.w;
        m = fmaxf(m, fmaxf(fmaxf(v.x, v.y), fmaxf(v.z, v.w)));
    }
    for (int off = 32; off; off >>= 1) {
        s += __shfl_down(s, off);
        m = fmaxf(m, __shfl_down(m, off));
    }
    __shared__ float ss[4], sm[4];
    int wid = t >> 6;
    if ((t & 63) == 0) { ss[wid] = s; sm[wid] = m; }
    __syncthreads();
    if (t == 0) {
        float S = ss[0] + ss[1] + ss[2] + ss[3];
        float M = fmaxf(fmaxf(sm[0], sm[1]), fmaxf(sm[2], sm[3]));
        avgp[bc] = S * (1.f / (float)HWN);
        maxp[bc] = M;
    }
}

// ---------------- K2: SE gate ----------------
__global__ __launch_bounds__(256) void k_gate(const float* __restrict__ avgp,
                                              const float* __restrict__ maxp,
                                              const float* __restrict__ w1,
                                              const float* __restrict__ w2,
                                              float* __restrict__ gate) {
    int b = blockIdx.x, t = threadIdx.x;
    __shared__ float sa[CCH], sx[CCH], sh[32];
    sa[t] = avgp[b * CCH + t];
    sx[t] = maxp[b * CCH + t];
    __syncthreads();
    if (t < 32) {
        int r = t & 15;
        const float* src = (t < 16) ? sa : sx;
        float h = 0.f;
        for (int c = 0; c < CCH; ++c) h += w1[r * CCH + c] * src[c];
        sh[t] = fmaxf(h, 0.f);
    }
    __syncthreads();
    float g = 0.f;
#pragma unroll
    for (int r = 0; r < RR; ++r) g += w2[t * RR + r] * (sh[r] + sh[16 + r]);
    gate[b * CCH + t] = 1.f / (1.f + __expf(-g));
}

// ---------------- K-proj: fused q,k,v projections via bf16 MFMA (R7-identical) ----------
// vB in CHUNKED layout, natural j order: vB[b][jc][c][jo], jc = j>>3, jo = j&7.
__global__ __launch_bounds__(256) void k_proj(const float* __restrict__ x,
                                              const float* __restrict__ gate,
                                              const unsigned short* __restrict__ Wb,
                                              const float* __restrict__ vb,
                                              const float* __restrict__ qb,
                                              const float* __restrict__ kb,
                                              unsigned short* __restrict__ qT,
                                              unsigned short* __restrict__ kT,
                                              unsigned short* __restrict__ vB) {
    int b = blockIdx.x & 7;              // XCD swizzle: batch <-> XCD
    int n0 = (blockIdx.x >> 3) << 6;
    int t = threadIdx.x;
    int w = t >> 6, l = t & 63, quad = l >> 4, ln = l & 15;

    __shared__ __align__(16) unsigned short xs_t[64][72];    // [n_local][c_local] bf16
    __shared__ __align__(16) unsigned short vtile[256 * 72]; // [m][n_local] bf16, stride 72
    __shared__ float qk_s[32][66];   // q rows 0..15, k rows 16..31 (fp32)

    const f32x4 zf = {0.f, 0.f, 0.f, 0.f};
    f32x4 acc[18];
#pragma unroll
    for (int mt = 0; mt < 18; ++mt) acc[mt] = zf;

    for (int cc = 0; cc < 4; ++cc) {
        __syncthreads();
#pragma unroll
        for (int it = 0; it < 4; ++it) {
            int idx = it * 256 + t;
            int cl = idx >> 4, nq = idx & 15;
            int c = cc * 64 + cl;
            float g = gate[b * CCH + c];
            float4 v = *(const float4*)(x + (((size_t)(b * CCH + c)) << 12) + n0 + nq * 4);
            xs_t[nq * 4 + 0][cl] = f2bf(v.x * g);
            xs_t[nq * 4 + 1][cl] = f2bf(v.y * g);
            xs_t[nq * 4 + 2][cl] = f2bf(v.z * g);
            xs_t[nq * 4 + 3][cl] = f2bf(v.w * g);
        }
        __syncthreads();

        short8 bfrag[2];
#pragma unroll
        for (int kc = 0; kc < 2; ++kc)
            bfrag[kc] = *(const short8*)&xs_t[w * 16 + ln][kc * 32 + quad * 8];

#pragma unroll
        for (int mt = 0; mt < 18; ++mt) {
#pragma unroll
            for (int kc = 0; kc < 2; ++kc) {
                short8 af = *(const short8*)(Wb + ((size_t)(mt * 16 + ln)) * 256 + cc * 64 + kc * 32 + quad * 8);
                acc[mt] = __builtin_amdgcn_mfma_f32_16x16x32_bf16(af, bfrag[kc], acc[mt], 0, 0, 0);
            }
        }
    }

    // v rows -> vtile[m][n_local]
#pragma unroll
    for (int mt = 0; mt < 16; ++mt) {
#pragma unroll
        for (int r = 0; r < 4; ++r) {
            int m = mt * 16 + quad * 4 + r;
            vtile[m * 72 + w * 16 + ln] = f2bf(acc[mt][r] + vb[m]);
        }
    }
    // q/k -> LDS for transpose
#pragma unroll
    for (int r = 0; r < 4; ++r) {
        qk_s[quad * 4 + r][w * 16 + ln] = acc[16][r];
        qk_s[16 + quad * 4 + r][w * 16 + ln] = acc[17][r];
    }
    __syncthreads();

    // stream vtile -> vB chunks: thread t = c; 8 x 16B stores, 1KB coalesced segments
    {
        unsigned short* vBp = vB + (((size_t)b) << 20);
        int c = t;
#pragma unroll
        for (int Q = 0; Q < 8; ++Q) {
            short8 v8 = *(const short8*)(vtile + c * 72 + Q * 8);
            *(short8*)(vBp + ((size_t)((((n0 >> 3) + Q) << 8) + c) << 3)) = v8;
        }
    }
    if (t < 128) {
        int isK = t >> 6;
        int n = t & 63;
        const float* bias = isK ? kb : qb;
        unsigned u32[8];
#pragma unroll
        for (int j = 0; j < 8; ++j) {
            unsigned lo = f2bf(qk_s[isK * 16 + 2 * j][n] + bias[2 * j]);
            unsigned hi = f2bf(qk_s[isK * 16 + 2 * j + 1][n] + bias[2 * j + 1]);
            u32[j] = lo | (hi << 16);
        }
        unsigned short* dst = (isK ? kT : qT) + ((size_t)(b * HWN + n0 + n)) * RR;
        uint4 d0 = {u32[0], u32[1], u32[2], u32[3]};
        uint4 d1 = {u32[4], u32[5], u32[6], u32[7]};
        ((uint4*)dst)[0] = d0;
        ((uint4*)dst)[1] = d1;
    }
}

// ---------------- K-attn: MFMA flash attention — (64c x 32i) waves, 2 blocks/CU ---------
// R4 post-mortem: (64c x 64i) waves -> only 2048 waves exist in the whole problem =
// 2 waves/SIMD in ONE barrier domain -> latency exposure ate the traffic gains
// (MfmaUtil AND VALUBusy both dropped). Traffic model itself confirmed (FETCH 29->26GB).
// THIS ROUND: (64c x 32i) waves — same 32-f32 acc as R3 (VGPR ~R3 level) but:
//   - P-LDS reads HALVE vs R3: 16 waves/CU x 32i x 4096j x 2B = 4MB/CU (~20us), 4 b128
//     per chunk per wave (was 8).
//   - V-L2 at R3 level (4MB/CU ~30us): block = 8 waves = 4 cg(64c) x 2 ih(32i) =
//     (256c x 64i), grid 512 = 2 blocks/CU; ih-pair waves issue identical V/K loads in
//     the same phase -> 2nd is L1-hit.
//   - Occupancy restored to R3's healthy shape: 16 waves/CU, 2 independent barrier
//     domains. MFMA count identical to R3 (18432/CU ~9us).
// Superstep structure (1 barrier per 128j), register chunk-dbuf, race-free 4-buf P LDS
// all unchanged from R2/R3. P LDS: chunk-major [jc 8][i 64][jo 8], 8KB/buf x 4.
__global__ __launch_bounds__(512, 4) void k_attn(const unsigned short* __restrict__ qT,
                                                 const unsigned short* __restrict__ kT,
                                                 const unsigned short* __restrict__ vB,
                                                 const float* __restrict__ x,
                                                 const float* __restrict__ gate,
                                                 const float* __restrict__ gamma,
                                                 float* __restrict__ out) {
    int b = blockIdx.x & 7;
    int i0 = (blockIdx.x >> 3) << 6;     // 64-i tile
    int t = threadIdx.x;
    int w = __builtin_amdgcn_readfirstlane(t >> 6);   // wave-uniform -> SGPR
    int l = t & 63;
    int quad = l >> 4, ln = l & 15;
    int cg = w >> 1;                     // c-group (0..3): PV c-range AND S j-tile (jsub)
    int ih = w & 1;                      // i-half (0..1): S i-range AND PV i-range
    int c0 = cg * 64;                    // PV c-range: 64 wide

    __shared__ __align__(16) unsigned short p_lds[4][4096];   // 4 bufs, chunk-major, 8KB each
    __shared__ float l_s[4][68];

    const short8 zs = {0, 0, 0, 0, 0, 0, 0, 0};
    const f32x4 zf = {0.f, 0.f, 0.f, 0.f};

    // two persistent Q B-frags: B[k=d=quad*8+kk][n=i], i = i0 + ih*32 + u*16 + ln
    short8 bq[2];
    bq[0] = zs; bq[1] = zs;
    if (quad < 2) {
#pragma unroll
        for (int u = 0; u < 2; ++u)
            bq[u] = *(const short8*)(qT + (((size_t)(b * HWN + i0 + ih * 32 + u * 16 + ln)) << 4) + (quad << 3));
    }

    f32x4 acc[4][2];   // [cs][is]: c = c0+cs*16+quad*4+r, i = ih*32+is*16+ln
#pragma unroll
    for (int cs = 0; cs < 4; ++cs)
#pragma unroll
        for (int is = 0; is < 2; ++is) acc[cs][is] = zf;
    float lsum[2] = {0.f, 0.f};

    const float c1 = 1.44269504f;      // log2(e)
    const float c0e = -11.5415603f;    // -8*log2(e): fixed shift, cancels in p/l

    // uniform (SGPR) bases + loop-invariant per-lane (VGPR) offsets, ushort units
    const unsigned short* kb_u = kT + ((size_t)(b * HWN)) * RR;
    const int kln = ((cg * 16 + ln) << 4) + (quad << 3);
    const unsigned short* vb_u = vB + (((size_t)b) << 20) + ((size_t)c0 << 3);
    int vln[8];
#pragma unroll
    for (int ks = 0; ks < 2; ++ks)
#pragma unroll
        for (int cs = 0; cs < 4; ++cs)
            vln[ks * 4 + cs] = (((ks * 4 + quad) << 8) + cs * 16 + ln) << 3;

    // P LDS offsets (ushort units), layout offset(i,j) = ((j>>3)*64 + i)*8 + (j&7)
    // store: j = cg*16 + quad*4 + r, i = ih*32 + u*16 + ln  -> soff + u*128
    int soff = ((cg * 2 + (quad >> 1)) * 64 + ih * 32 + ln) * 8 + (quad & 1) * 4;
    // read: jc = ks*4 + quad, i = ih*32 + is*16 + ln  -> rbase + ks*2048 + is*128
    int rbase = quad * 512 + (ih * 32 + ln) * 8;

    short8 akA = zs, akB = zs;          // K A-frags: chunk0 / chunk1 of current superstep
    short8 avA[8], avB[8];              // V A-frags: chunk0 / chunk1, [ks*4+cs]

    auto load_ak = [&](short8& ak, int j0) {
        if (quad < 2) ak = *(const short8*)(kb_u + ((j0 << 4) + kln));
    };
    auto load_av = [&](short8 (&av)[8], int j0) {
        const unsigned short* vp = vb_u + (j0 << 8);   // scalar advance
#pragma unroll
        for (int u = 0; u < 8; ++u) av[u] = *(const short8*)(vp + vln[u]);
    };

    load_ak(akA, 0);
    load_ak(akB, 64);
    load_av(avA, 0);
    load_av(avB, 64);

    // exp + pack + store one S^T tile (chunk pbuf, i-subtile u)
    auto finish_s = [&](const f32x4& sf, unsigned short* pbuf, int u) {
        float p0 = exp2f(fmaf(sf[0], c1, c0e));
        float p1 = exp2f(fmaf(sf[1], c1, c0e));
        float p2 = exp2f(fmaf(sf[2], c1, c0e));
        float p3 = exp2f(fmaf(sf[3], c1, c0e));
        lsum[u] += (p0 + p1) + (p2 + p3);
        uint2 pk;
        asm("v_cvt_pk_bf16_f32 %0, %1, %2" : "=v"(pk.x) : "v"(p0), "v"(p1));
        asm("v_cvt_pk_bf16_f32 %0, %1, %2" : "=v"(pk.y) : "v"(p2), "v"(p3));
        *(uint2*)(pbuf + soff + u * 128) = pk;
    };

    // PV over one 64-j chunk: 4 b128 P reads + 16 MFMAs (c 64 x i 32)
    auto pv = [&](const short8 (&av)[8], const unsigned short* pbuf) {
#pragma unroll
        for (int ks = 0; ks < 2; ++ks) {
            short8 bp[2];
#pragma unroll
            for (int is = 0; is < 2; ++is)
                bp[is] = *(const short8*)(pbuf + rbase + ks * 2048 + is * 128);
#pragma unroll
            for (int cs = 0; cs < 4; ++cs)
#pragma unroll
                for (int is = 0; is < 2; ++is)
                    acc[cs][is] = __builtin_amdgcn_mfma_f32_16x16x32_bf16(av[ks * 4 + cs], bp[is], acc[cs][is], 0, 0, 0);
        }
    };

    for (int jt = 0; jt < 32; ++jt) {
        unsigned short* pb0 = &p_lds[(jt & 1) * 2 + 0][0];
        unsigned short* pb1 = &p_lds[(jt & 1) * 2 + 1][0];

        // ---- QK both chunks x 2 i-subtiles (consumes akA/akB), P stores ----
        f32x4 sA[2], sB[2];
#pragma unroll
        for (int u = 0; u < 2; ++u)
            sA[u] = __builtin_amdgcn_mfma_f32_16x16x32_bf16(akA, bq[u], zf, 0, 0, 0);
#pragma unroll
        for (int u = 0; u < 2; ++u)
            sB[u] = __builtin_amdgcn_mfma_f32_16x16x32_bf16(akB, bq[u], zf, 0, 0, 0);
#pragma unroll
        for (int u = 0; u < 2; ++u) finish_s(sA[u], pb0, u);
#pragma unroll
        for (int u = 0; u < 2; ++u) finish_s(sB[u], pb1, u);

        __syncthreads();   // ONE barrier per 128 j: P pair visible; prev prefetches drained

        bool pf = jt < 31;
        int j0n = (jt + 1) << 7;
        // K prefetch for next superstep (akA/akB free after QK above)
        if (pf) { load_ak(akA, j0n); load_ak(akB, j0n + 64); }

        // PV chunk0 (consumes avA) then refill avA; PV chunk1 then refill avB
        pv(avA, pb0);
        if (pf) load_av(avA, j0n);
        pv(avB, pb1);
        if (pf) load_av(avB, j0n + 64);
    }

    // l reduction: lane's lsum[u] covers its 4 j's (tile cg) at i = ih*32 + u*16 + ln
#pragma unroll
    for (int u = 0; u < 2; ++u) {
        lsum[u] += __shfl_xor(lsum[u], 16, 64);
        lsum[u] += __shfl_xor(lsum[u], 32, 64);
    }
    if (l < 16) {
#pragma unroll
        for (int u = 0; u < 2; ++u)
            l_s[cg][ih * 32 + u * 16 + l] = lsum[u];
    }
    __syncthreads();

    float g = gamma[0];
    float rinv[2];
#pragma unroll
    for (int is = 0; is < 2; ++is) {
        int i = ih * 32 + is * 16 + ln;
        float lf = (l_s[0][i] + l_s[1][i]) + (l_s[2][i] + l_s[3][i]);
        rinv[is] = g / lf;
    }

    // epilogue: out = gamma*o/l + x*gate
#pragma unroll
    for (int cs = 0; cs < 4; ++cs) {
#pragma unroll
        for (int r = 0; r < 4; ++r) {
            int c = c0 + cs * 16 + quad * 4 + r;
            float gc = gate[b * CCH + c];
            size_t rowoff = (((size_t)(b * CCH + c)) << 12) + i0;
            float* po = out + rowoff;
            const float* px = x + rowoff;
#pragma unroll
            for (int is = 0; is < 2; ++is) {
                int idx = ih * 32 + is * 16 + ln;
                po[idx] = acc[cs][is][r] * rinv[is] + px[idx] * gc;
            }
        }
    }
}

extern "C" void kernel_launch(void* const* d_in, const int* in_sizes, int n_in,
                              void* d_out, int out_size, void* d_ws, size_t ws_size,
                              hipStream_t stream) {
    const float* x = (const float*)d_in[0];
    const float* w1 = (const float*)d_in[1];
    const float* w2 = (const float*)d_in[2];
    const float* qw = (const float*)d_in[3];
    const float* qb = (const float*)d_in[4];
    const float* kw = (const float*)d_in[5];
    const float* kb = (const float*)d_in[6];
    const float* vw = (const float*)d_in[7];
    const float* vb = (const float*)d_in[8];
    const float* gamma = (const float*)d_in[9];
    float* out = (float*)d_out;
    char* ws = (char*)d_ws;

    float* avgp = (float*)(ws);                        // 8 KB
    float* maxp = (float*)(ws + 8192);                 // 8 KB
    float* gate = (float*)(ws + 16384);                // 8 KB
    unsigned short* Wb = (unsigned short*)(ws + 24576);               // [288][256] bf16
    unsigned short* qT = (unsigned short*)(ws + 24576 + 147456);      // 1 MB [b][n][16]
    unsigned short* kT = (unsigned short*)(ws + 24576 + 147456 + 1048576);
    unsigned short* vB = (unsigned short*)(ws + 24576 + 147456 + 2097152);  // 16.8 MB chunked

    k_pool<<<2048, 256, 0, stream>>>(x, avgp, maxp, vw, qw, kw, Wb);  // + fused wprep
    k_gate<<<8, 256, 0, stream>>>(avgp, maxp, w1, w2, gate);
    k_proj<<<512, 256, 0, stream>>>(x, gate, Wb, vb, qb, kb, qT, kT, vB);
    k_attn<<<512, 512, 0, stream>>>(qT, kT, vB, x, gate, gamma, out);
}

// Round 6
// 336.880 us; speedup vs baseline: 1.2616x; 1.2616x over previous
//
#include <hip/hip_runtime.h>
#include <hip/hip_bf16.h>
#include <math.h>

#define BB 8
#define CCH 256
#define HWN 4096
#define RR 16

typedef __attribute__((ext_vector_type(8))) short short8;   // 8 bf16 = K=32 MFMA A/B frag (4 VGPRs)
typedef __attribute__((ext_vector_type(4))) float f32x4;    // MFMA C/D frag

static __device__ __forceinline__ unsigned short f2bf(float x) {
    union { float f; unsigned u; } v; v.f = x;
    return (unsigned short)((v.u + 0x8000u) >> 16);   // round-half-up bf16
}

// ---------------- K1: avg+max pool per (b,c); blocks 0..287 also pack Wb (fused wprep) ----
__global__ __launch_bounds__(256) void k_pool(const float* __restrict__ x,
                                              float* __restrict__ avgp,
                                              float* __restrict__ maxp,
                                              const float* __restrict__ vw,
                                              const float* __restrict__ qw,
                                              const float* __restrict__ kw,
                                              unsigned short* __restrict__ Wb) {
    int bc = blockIdx.x;
    int t = threadIdx.x;
    if (bc < 288) {
        int idx = bc * 256 + t;
        int m = idx >> 8, c = idx & 255;
        float v;
        if (m < 256) v = vw[idx];
        else if (m < 272) v = qw[(m - 256) * 256 + c];
        else v = kw[(m - 272) * 256 + c];
        Wb[idx] = f2bf(v);
    }
    const float4* p = (const float4*)(x + (size_t)bc * HWN);
    float s = 0.f, m = -INFINITY;
#pragma unroll
    for (int i = 0; i < 4; ++i) {
        float4 v = p[t + 256 * i];
        s += v.x + v.y + v.z + v.w;
        m = fmaxf(m, fmaxf(fmaxf(v.x, v.y), fmaxf(v.z, v.w)));
    }
    for (int off = 32; off; off >>= 1) {
        s += __shfl_down(s, off);
        m = fmaxf(m, __shfl_down(m, off));
    }
    __shared__ float ss[4], sm[4];
    int wid = t >> 6;
    if ((t & 63) == 0) { ss[wid] = s; sm[wid] = m; }
    __syncthreads();
    if (t == 0) {
        float S = ss[0] + ss[1] + ss[2] + ss[3];
        float M = fmaxf(fmaxf(sm[0], sm[1]), fmaxf(sm[2], sm[3]));
        avgp[bc] = S * (1.f / (float)HWN);
        maxp[bc] = M;
    }
}

// ---------------- K2: SE gate ----------------
__global__ __launch_bounds__(256) void k_gate(const float* __restrict__ avgp,
                                              const float* __restrict__ maxp,
                                              const float* __restrict__ w1,
                                              const float* __restrict__ w2,
                                              float* __restrict__ gate) {
    int b = blockIdx.x, t = threadIdx.x;
    __shared__ float sa[CCH], sx[CCH], sh[32];
    sa[t] = avgp[b * CCH + t];
    sx[t] = maxp[b * CCH + t];
    __syncthreads();
    if (t < 32) {
        int r = t & 15;
        const float* src = (t < 16) ? sa : sx;
        float h = 0.f;
        for (int c = 0; c < CCH; ++c) h += w1[r * CCH + c] * src[c];
        sh[t] = fmaxf(h, 0.f);
    }
    __syncthreads();
    float g = 0.f;
#pragma unroll
    for (int r = 0; r < RR; ++r) g += w2[t * RR + r] * (sh[r] + sh[16 + r]);
    gate[b * CCH + t] = 1.f / (1.f + __expf(-g));
}

// ---------------- K-proj: fused q,k,v projections via bf16 MFMA (R7-identical) ----------
// vB in CHUNKED layout, natural j order: vB[b][jc][c][jo], jc = j>>3, jo = j&7.
__global__ __launch_bounds__(256) void k_proj(const float* __restrict__ x,
                                              const float* __restrict__ gate,
                                              const unsigned short* __restrict__ Wb,
                                              const float* __restrict__ vb,
                                              const float* __restrict__ qb,
                                              const float* __restrict__ kb,
                                              unsigned short* __restrict__ qT,
                                              unsigned short* __restrict__ kT,
                                              unsigned short* __restrict__ vB) {
    int b = blockIdx.x & 7;              // XCD swizzle: batch <-> XCD
    int n0 = (blockIdx.x >> 3) << 6;
    int t = threadIdx.x;
    int w = t >> 6, l = t & 63, quad = l >> 4, ln = l & 15;

    __shared__ __align__(16) unsigned short xs_t[64][72];    // [n_local][c_local] bf16
    __shared__ __align__(16) unsigned short vtile[256 * 72]; // [m][n_local] bf16, stride 72
    __shared__ float qk_s[32][66];   // q rows 0..15, k rows 16..31 (fp32)

    const f32x4 zf = {0.f, 0.f, 0.f, 0.f};
    f32x4 acc[18];
#pragma unroll
    for (int mt = 0; mt < 18; ++mt) acc[mt] = zf;

    for (int cc = 0; cc < 4; ++cc) {
        __syncthreads();
#pragma unroll
        for (int it = 0; it < 4; ++it) {
            int idx = it * 256 + t;
            int cl = idx >> 4, nq = idx & 15;
            int c = cc * 64 + cl;
            float g = gate[b * CCH + c];
            float4 v = *(const float4*)(x + (((size_t)(b * CCH + c)) << 12) + n0 + nq * 4);
            xs_t[nq * 4 + 0][cl] = f2bf(v.x * g);
            xs_t[nq * 4 + 1][cl] = f2bf(v.y * g);
            xs_t[nq * 4 + 2][cl] = f2bf(v.z * g);
            xs_t[nq * 4 + 3][cl] = f2bf(v.w * g);
        }
        __syncthreads();

        short8 bfrag[2];
#pragma unroll
        for (int kc = 0; kc < 2; ++kc)
            bfrag[kc] = *(const short8*)&xs_t[w * 16 + ln][kc * 32 + quad * 8];

#pragma unroll
        for (int mt = 0; mt < 18; ++mt) {
#pragma unroll
            for (int kc = 0; kc < 2; ++kc) {
                short8 af = *(const short8*)(Wb + ((size_t)(mt * 16 + ln)) * 256 + cc * 64 + kc * 32 + quad * 8);
                acc[mt] = __builtin_amdgcn_mfma_f32_16x16x32_bf16(af, bfrag[kc], acc[mt], 0, 0, 0);
            }
        }
    }

    // v rows -> vtile[m][n_local]
#pragma unroll
    for (int mt = 0; mt < 16; ++mt) {
#pragma unroll
        for (int r = 0; r < 4; ++r) {
            int m = mt * 16 + quad * 4 + r;
            vtile[m * 72 + w * 16 + ln] = f2bf(acc[mt][r] + vb[m]);
        }
    }
    // q/k -> LDS for transpose
#pragma unroll
    for (int r = 0; r < 4; ++r) {
        qk_s[quad * 4 + r][w * 16 + ln] = acc[16][r];
        qk_s[16 + quad * 4 + r][w * 16 + ln] = acc[17][r];
    }
    __syncthreads();

    // stream vtile -> vB chunks: thread t = c; 8 x 16B stores, 1KB coalesced segments
    {
        unsigned short* vBp = vB + (((size_t)b) << 20);
        int c = t;
#pragma unroll
        for (int Q = 0; Q < 8; ++Q) {
            short8 v8 = *(const short8*)(vtile + c * 72 + Q * 8);
            *(short8*)(vBp + ((size_t)((((n0 >> 3) + Q) << 8) + c) << 3)) = v8;
        }
    }
    if (t < 128) {
        int isK = t >> 6;
        int n = t & 63;
        const float* bias = isK ? kb : qb;
        unsigned u32[8];
#pragma unroll
        for (int j = 0; j < 8; ++j) {
            unsigned lo = f2bf(qk_s[isK * 16 + 2 * j][n] + bias[2 * j]);
            unsigned hi = f2bf(qk_s[isK * 16 + 2 * j + 1][n] + bias[2 * j + 1]);
            u32[j] = lo | (hi << 16);
        }
        unsigned short* dst = (isK ? kT : qT) + ((size_t)(b * HWN + n0 + n)) * RR;
        uint4 d0 = {u32[0], u32[1], u32[2], u32[3]};
        uint4 d1 = {u32[4], u32[5], u32[6], u32[7]};
        ((uint4*)dst)[0] = d0;
        ((uint4*)dst)[1] = d1;
    }
}

// ---------------- K-attn: (64c x 32i) waves + SINGLE V buffer (rolling half-refill) ------
// R5 post-mortem: geometry was right (P-LDS halves) but avA[8]+avB[8]=64 regs blew the
// 4-waves/SIMD unified budget (~128) -> compiler spilled V frags to scratch every iter
// (FETCH 32->461MB, WRITE 32->320MB). Fix: ONE av[8] (32 regs, = R3's V footprint).
// PV split by ks-half: 8 MFMAs consume av[ks*4..ks*4+3], then that half is refilled for
// the next chunk; the following 8 MFMAs + K-prefetch hide the (L1/L2-hit) refill latency.
// R3 proved the compiler handles refill-after-consume without hoist-spill (same pattern).
// Corrected pipe model (per CU): MFMA 37us (19.4cyc/MFMA/SIMD), P-LDS 40->20us (this
// geometry), V-L2 30us, VALU ~13us; different HW units -> target better overlap than
// R3's 92.7. K dbuf kept (16 regs). Occupancy target: 16 waves/CU, 2 barrier domains.
// P LDS: chunk-major [jc 8][i 64][jo 8], 8KB/buf x 4 bufs (pair jt&1; race-free as R2).
__global__ __launch_bounds__(512, 4) void k_attn(const unsigned short* __restrict__ qT,
                                                 const unsigned short* __restrict__ kT,
                                                 const unsigned short* __restrict__ vB,
                                                 const float* __restrict__ x,
                                                 const float* __restrict__ gate,
                                                 const float* __restrict__ gamma,
                                                 float* __restrict__ out) {
    int b = blockIdx.x & 7;
    int i0 = (blockIdx.x >> 3) << 6;     // 64-i tile
    int t = threadIdx.x;
    int w = __builtin_amdgcn_readfirstlane(t >> 6);   // wave-uniform -> SGPR
    int l = t & 63;
    int quad = l >> 4, ln = l & 15;
    int cg = w >> 1;                     // c-group (0..3): PV c-range AND S j-tile (jsub)
    int ih = w & 1;                      // i-half (0..1): S i-range AND PV i-range
    int c0 = cg * 64;                    // PV c-range: 64 wide

    __shared__ __align__(16) unsigned short p_lds[4][4096];   // 4 bufs, chunk-major, 8KB each
    __shared__ float l_s[4][68];

    const short8 zs = {0, 0, 0, 0, 0, 0, 0, 0};
    const f32x4 zf = {0.f, 0.f, 0.f, 0.f};

    // two persistent Q B-frags: B[k=d=quad*8+kk][n=i], i = i0 + ih*32 + u*16 + ln
    short8 bq[2];
    bq[0] = zs; bq[1] = zs;
    if (quad < 2) {
#pragma unroll
        for (int u = 0; u < 2; ++u)
            bq[u] = *(const short8*)(qT + (((size_t)(b * HWN + i0 + ih * 32 + u * 16 + ln)) << 4) + (quad << 3));
    }

    f32x4 acc[4][2];   // [cs][is]: c = c0+cs*16+quad*4+r, i = ih*32+is*16+ln
#pragma unroll
    for (int cs = 0; cs < 4; ++cs)
#pragma unroll
        for (int is = 0; is < 2; ++is) acc[cs][is] = zf;
    float lsum[2] = {0.f, 0.f};

    const float c1 = 1.44269504f;      // log2(e)
    const float c0e = -11.5415603f;    // -8*log2(e): fixed shift, cancels in p/l

    // uniform (SGPR) bases + loop-invariant per-lane (VGPR) offsets, ushort units
    const unsigned short* kb_u = kT + ((size_t)(b * HWN)) * RR;
    const int kln = ((cg * 16 + ln) << 4) + (quad << 3);
    const unsigned short* vb_u = vB + (((size_t)b) << 20) + ((size_t)c0 << 3);
    int vln[8];
#pragma unroll
    for (int ks = 0; ks < 2; ++ks)
#pragma unroll
        for (int cs = 0; cs < 4; ++cs)
            vln[ks * 4 + cs] = (((ks * 4 + quad) << 8) + cs * 16 + ln) << 3;

    // P LDS offsets (ushort units), layout offset(i,j) = ((j>>3)*64 + i)*8 + (j&7)
    // store: j = cg*16 + quad*4 + r, i = ih*32 + u*16 + ln  -> soff + u*128
    int soff = ((cg * 2 + (quad >> 1)) * 64 + ih * 32 + ln) * 8 + (quad & 1) * 4;
    // read: jc = ks*4 + quad, i = ih*32 + is*16 + ln  -> rbase + ks*2048 + is*128
    int rbase = quad * 512 + (ih * 32 + ln) * 8;

    short8 akA = zs, akB = zs;          // K A-frags: chunk0 / chunk1 of current superstep
    short8 av[8];                        // SINGLE V A-frag buffer, [ks*4+cs]

    auto load_ak = [&](short8& ak, int j0) {
        if (quad < 2) ak = *(const short8*)(kb_u + ((j0 << 4) + kln));
    };
    // refill one ks-half of av for chunk at j0
    auto load_av_half = [&](int ks, int j0) {
        const unsigned short* vp = vb_u + (j0 << 8);   // scalar advance
#pragma unroll
        for (int cs = 0; cs < 4; ++cs) av[ks * 4 + cs] = *(const short8*)(vp + vln[ks * 4 + cs]);
    };

    load_ak(akA, 0);
    load_ak(akB, 64);
    load_av_half(0, 0);
    load_av_half(1, 0);

    // exp + pack + store one S^T tile (chunk pbuf, i-subtile u)
    auto finish_s = [&](const f32x4& sf, unsigned short* pbuf, int u) {
        float p0 = exp2f(fmaf(sf[0], c1, c0e));
        float p1 = exp2f(fmaf(sf[1], c1, c0e));
        float p2 = exp2f(fmaf(sf[2], c1, c0e));
        float p3 = exp2f(fmaf(sf[3], c1, c0e));
        lsum[u] += (p0 + p1) + (p2 + p3);
        uint2 pk;
        asm("v_cvt_pk_bf16_f32 %0, %1, %2" : "=v"(pk.x) : "v"(p0), "v"(p1));
        asm("v_cvt_pk_bf16_f32 %0, %1, %2" : "=v"(pk.y) : "v"(p2), "v"(p3));
        *(uint2*)(pbuf + soff + u * 128) = pk;
    };

    // PV over one ks-half of one 64-j chunk: 2 b128 P reads + 8 MFMAs (c 64 x i 32)
    auto pv_ks = [&](int ks, const unsigned short* pbuf) {
        short8 bp[2];
#pragma unroll
        for (int is = 0; is < 2; ++is)
            bp[is] = *(const short8*)(pbuf + rbase + ks * 2048 + is * 128);
#pragma unroll
        for (int cs = 0; cs < 4; ++cs)
#pragma unroll
            for (int is = 0; is < 2; ++is)
                acc[cs][is] = __builtin_amdgcn_mfma_f32_16x16x32_bf16(av[ks * 4 + cs], bp[is], acc[cs][is], 0, 0, 0);
    };

    for (int jt = 0; jt < 32; ++jt) {
        int j0 = jt << 7;
        unsigned short* pb0 = &p_lds[(jt & 1) * 2 + 0][0];
        unsigned short* pb1 = &p_lds[(jt & 1) * 2 + 1][0];

        // ---- QK both chunks x 2 i-subtiles (consumes akA/akB), P stores ----
        f32x4 sA[2], sB[2];
#pragma unroll
        for (int u = 0; u < 2; ++u)
            sA[u] = __builtin_amdgcn_mfma_f32_16x16x32_bf16(akA, bq[u], zf, 0, 0, 0);
#pragma unroll
        for (int u = 0; u < 2; ++u)
            sB[u] = __builtin_amdgcn_mfma_f32_16x16x32_bf16(akB, bq[u], zf, 0, 0, 0);
#pragma unroll
        for (int u = 0; u < 2; ++u) finish_s(sA[u], pb0, u);
#pragma unroll
        for (int u = 0; u < 2; ++u) finish_s(sB[u], pb1, u);

        __syncthreads();   // ONE barrier per 128 j: P pair visible; prev prefetches drained

        bool pf = jt < 31;
        int j0n = j0 + 128;
        // K prefetch for next superstep (akA/akB free after QK above)
        if (pf) { load_ak(akA, j0n); load_ak(akB, j0n + 64); }

        // PV rolling half-refill: consume av half -> refill it for the next chunk;
        // the next 8 MFMAs (+ K prefetch issue) hide each refill's L1/L2 latency.
        pv_ks(0, pb0);
        load_av_half(0, j0 + 64);        // chunk1 ks=0 (always valid: j0+64 <= 4032)
        pv_ks(1, pb0);
        load_av_half(1, j0 + 64);        // chunk1 ks=1
        pv_ks(0, pb1);
        if (pf) load_av_half(0, j0n);    // next superstep chunk0 ks=0
        pv_ks(1, pb1);
        if (pf) load_av_half(1, j0n);    // next superstep chunk0 ks=1
    }

    // l reduction: lane's lsum[u] covers its 4 j's (tile cg) at i = ih*32 + u*16 + ln
#pragma unroll
    for (int u = 0; u < 2; ++u) {
        lsum[u] += __shfl_xor(lsum[u], 16, 64);
        lsum[u] += __shfl_xor(lsum[u], 32, 64);
    }
    if (l < 16) {
#pragma unroll
        for (int u = 0; u < 2; ++u)
            l_s[cg][ih * 32 + u * 16 + l] = lsum[u];
    }
    __syncthreads();

    float g = gamma[0];
    float rinv[2];
#pragma unroll
    for (int is = 0; is < 2; ++is) {
        int i = ih * 32 + is * 16 + ln;
        float lf = (l_s[0][i] + l_s[1][i]) + (l_s[2][i] + l_s[3][i]);
        rinv[is] = g / lf;
    }

    // epilogue: out = gamma*o/l + x*gate
#pragma unroll
    for (int cs = 0; cs < 4; ++cs) {
#pragma unroll
        for (int r = 0; r < 4; ++r) {
            int c = c0 + cs * 16 + quad * 4 + r;
            float gc = gate[b * CCH + c];
            size_t rowoff = (((size_t)(b * CCH + c)) << 12) + i0;
            float* po = out + rowoff;
            const float* px = x + rowoff;
#pragma unroll
            for (int is = 0; is < 2; ++is) {
                int idx = ih * 32 + is * 16 + ln;
                po[idx] = acc[cs][is][r] * rinv[is] + px[idx] * gc;
            }
        }
    }
}

extern "C" void kernel_launch(void* const* d_in, const int* in_sizes, int n_in,
                              void* d_out, int out_size, void* d_ws, size_t ws_size,
                              hipStream_t stream) {
    const float* x = (const float*)d_in[0];
    const float* w1 = (const float*)d_in[1];
    const float* w2 = (const float*)d_in[2];
    const float* qw = (const float*)d_in[3];
    const float* qb = (const float*)d_in[4];
    const float* kw = (const float*)d_in[5];
    const float* kb = (const float*)d_in[6];
    const float* vw = (const float*)d_in[7];
    const float* vb = (const float*)d_in[8];
    const float* gamma = (const float*)d_in[9];
    float* out = (float*)d_out;
    char* ws = (char*)d_ws;

    float* avgp = (float*)(ws);                        // 8 KB
    float* maxp = (float*)(ws + 8192);                 // 8 KB
    float* gate = (float*)(ws + 16384);                // 8 KB
    unsigned short* Wb = (unsigned short*)(ws + 24576);               // [288][256] bf16
    unsigned short* qT = (unsigned short*)(ws + 24576 + 147456);      // 1 MB [b][n][16]
    unsigned short* kT = (unsigned short*)(ws + 24576 + 147456 + 1048576);
    unsigned short* vB = (unsigned short*)(ws + 24576 + 147456 + 2097152);  // 16.8 MB chunked

    k_pool<<<2048, 256, 0, stream>>>(x, avgp, maxp, vw, qw, kw, Wb);  // + fused wprep
    k_gate<<<8, 256, 0, stream>>>(avgp, maxp, w1, w2, gate);
    k_proj<<<512, 256, 0, stream>>>(x, gate, Wb, vb, qb, kb, qT, kT, vB);
    k_attn<<<512, 512, 0, stream>>>(qT, kT, vB, x, gate, gamma, out);
}

// Round 7
// 284.320 us; speedup vs baseline: 1.4949x; 1.1849x over previous
//
#include <hip/hip_runtime.h>
#include <hip/hip_bf16.h>
#include <math.h>

#define BB 8
#define CCH 256
#define HWN 4096
#define RR 16

typedef __attribute__((ext_vector_type(8))) short short8;   // 8 bf16 = K=32 MFMA A/B frag (4 VGPRs)
typedef __attribute__((ext_vector_type(4))) float f32x4;    // MFMA C/D frag

static __device__ __forceinline__ unsigned short f2bf(float x) {
    union { float f; unsigned u; } v; v.f = x;
    return (unsigned short)((v.u + 0x8000u) >> 16);   // round-half-up bf16
}

// ---------------- K1: avg+max pool per (b,c); blocks 0..287 also pack Wb (fused wprep) ----
__global__ __launch_bounds__(256) void k_pool(const float* __restrict__ x,
                                              float* __restrict__ avgp,
                                              float* __restrict__ maxp,
                                              const float* __restrict__ vw,
                                              const float* __restrict__ qw,
                                              const float* __restrict__ kw,
                                              unsigned short* __restrict__ Wb) {
    int bc = blockIdx.x;
    int t = threadIdx.x;
    if (bc < 288) {
        int idx = bc * 256 + t;
        int m = idx >> 8, c = idx & 255;
        float v;
        if (m < 256) v = vw[idx];
        else if (m < 272) v = qw[(m - 256) * 256 + c];
        else v = kw[(m - 272) * 256 + c];
        Wb[idx] = f2bf(v);
    }
    const float4* p = (const float4*)(x + (size_t)bc * HWN);
    float s = 0.f, m = -INFINITY;
#pragma unroll
    for (int i = 0; i < 4; ++i) {
        float4 v = p[t + 256 * i];
        s += v.x + v.y + v.z + v.w;
        m = fmaxf(m, fmaxf(fmaxf(v.x, v.y), fmaxf(v.z, v.w)));
    }
    for (int off = 32; off; off >>= 1) {
        s += __shfl_down(s, off);
        m = fmaxf(m, __shfl_down(m, off));
    }
    __shared__ float ss[4], sm[4];
    int wid = t >> 6;
    if ((t & 63) == 0) { ss[wid] = s; sm[wid] = m; }
    __syncthreads();
    if (t == 0) {
        float S = ss[0] + ss[1] + ss[2] + ss[3];
        float M = fmaxf(fmaxf(sm[0], sm[1]), fmaxf(sm[2], sm[3]));
        avgp[bc] = S * (1.f / (float)HWN);
        maxp[bc] = M;
    }
}

// ---------------- K2: SE gate ----------------
__global__ __launch_bounds__(256) void k_gate(const float* __restrict__ avgp,
                                              const float* __restrict__ maxp,
                                              const float* __restrict__ w1,
                                              const float* __restrict__ w2,
                                              float* __restrict__ gate) {
    int b = blockIdx.x, t = threadIdx.x;
    __shared__ float sa[CCH], sx[CCH], sh[32];
    sa[t] = avgp[b * CCH + t];
    sx[t] = maxp[b * CCH + t];
    __syncthreads();
    if (t < 32) {
        int r = t & 15;
        const float* src = (t < 16) ? sa : sx;
        float h = 0.f;
        for (int c = 0; c < CCH; ++c) h += w1[r * CCH + c] * src[c];
        sh[t] = fmaxf(h, 0.f);
    }
    __syncthreads();
    float g = 0.f;
#pragma unroll
    for (int r = 0; r < RR; ++r) g += w2[t * RR + r] * (sh[r] + sh[16 + r]);
    gate[b * CCH + t] = 1.f / (1.f + __expf(-g));
}

// ---------------- K-proj: fused q,k,v projections via bf16 MFMA (R7-identical) ----------
// vB in CHUNKED layout, natural j order: vB[b][jc][c][jo], jc = j>>3, jo = j&7.
__global__ __launch_bounds__(256) void k_proj(const float* __restrict__ x,
                                              const float* __restrict__ gate,
                                              const unsigned short* __restrict__ Wb,
                                              const float* __restrict__ vb,
                                              const float* __restrict__ qb,
                                              const float* __restrict__ kb,
                                              unsigned short* __restrict__ qT,
                                              unsigned short* __restrict__ kT,
                                              unsigned short* __restrict__ vB) {
    int b = blockIdx.x & 7;              // XCD swizzle: batch <-> XCD
    int n0 = (blockIdx.x >> 3) << 6;
    int t = threadIdx.x;
    int w = t >> 6, l = t & 63, quad = l >> 4, ln = l & 15;

    __shared__ __align__(16) unsigned short xs_t[64][72];    // [n_local][c_local] bf16
    __shared__ __align__(16) unsigned short vtile[256 * 72]; // [m][n_local] bf16, stride 72
    __shared__ float qk_s[32][66];   // q rows 0..15, k rows 16..31 (fp32)

    const f32x4 zf = {0.f, 0.f, 0.f, 0.f};
    f32x4 acc[18];
#pragma unroll
    for (int mt = 0; mt < 18; ++mt) acc[mt] = zf;

    for (int cc = 0; cc < 4; ++cc) {
        __syncthreads();
#pragma unroll
        for (int it = 0; it < 4; ++it) {
            int idx = it * 256 + t;
            int cl = idx >> 4, nq = idx & 15;
            int c = cc * 64 + cl;
            float g = gate[b * CCH + c];
            float4 v = *(const float4*)(x + (((size_t)(b * CCH + c)) << 12) + n0 + nq * 4);
            xs_t[nq * 4 + 0][cl] = f2bf(v.x * g);
            xs_t[nq * 4 + 1][cl] = f2bf(v.y * g);
            xs_t[nq * 4 + 2][cl] = f2bf(v.z * g);
            xs_t[nq * 4 + 3][cl] = f2bf(v.w * g);
        }
        __syncthreads();

        short8 bfrag[2];
#pragma unroll
        for (int kc = 0; kc < 2; ++kc)
            bfrag[kc] = *(const short8*)&xs_t[w * 16 + ln][kc * 32 + quad * 8];

#pragma unroll
        for (int mt = 0; mt < 18; ++mt) {
#pragma unroll
            for (int kc = 0; kc < 2; ++kc) {
                short8 af = *(const short8*)(Wb + ((size_t)(mt * 16 + ln)) * 256 + cc * 64 + kc * 32 + quad * 8);
                acc[mt] = __builtin_amdgcn_mfma_f32_16x16x32_bf16(af, bfrag[kc], acc[mt], 0, 0, 0);
            }
        }
    }

    // v rows -> vtile[m][n_local]
#pragma unroll
    for (int mt = 0; mt < 16; ++mt) {
#pragma unroll
        for (int r = 0; r < 4; ++r) {
            int m = mt * 16 + quad * 4 + r;
            vtile[m * 72 + w * 16 + ln] = f2bf(acc[mt][r] + vb[m]);
        }
    }
    // q/k -> LDS for transpose
#pragma unroll
    for (int r = 0; r < 4; ++r) {
        qk_s[quad * 4 + r][w * 16 + ln] = acc[16][r];
        qk_s[16 + quad * 4 + r][w * 16 + ln] = acc[17][r];
    }
    __syncthreads();

    // stream vtile -> vB chunks: thread t = c; 8 x 16B stores, 1KB coalesced segments
    {
        unsigned short* vBp = vB + (((size_t)b) << 20);
        int c = t;
#pragma unroll
        for (int Q = 0; Q < 8; ++Q) {
            short8 v8 = *(const short8*)(vtile + c * 72 + Q * 8);
            *(short8*)(vBp + ((size_t)((((n0 >> 3) + Q) << 8) + c) << 3)) = v8;
        }
    }
    if (t < 128) {
        int isK = t >> 6;
        int n = t & 63;
        const float* bias = isK ? kb : qb;
        unsigned u32[8];
#pragma unroll
        for (int j = 0; j < 8; ++j) {
            unsigned lo = f2bf(qk_s[isK * 16 + 2 * j][n] + bias[2 * j]);
            unsigned hi = f2bf(qk_s[isK * 16 + 2 * j + 1][n] + bias[2 * j + 1]);
            u32[j] = lo | (hi << 16);
        }
        unsigned short* dst = (isK ? kT : qT) + ((size_t)(b * HWN + n0 + n)) * RR;
        uint4 d0 = {u32[0], u32[1], u32[2], u32[3]};
        uint4 d1 = {u32[4], u32[5], u32[6], u32[7]};
        ((uint4*)dst)[0] = d0;
        ((uint4*)dst)[1] = d1;
    }
}

// ---------------- K-attn: (64c x 32i) waves, single V buf — launch_bounds FIX ----------
// R6 post-mortem: STILL spilling (FETCH 75GB, WRITE 76GB) at VGPR_Count=64. Cross-round
// evidence: (512,4) -> compiler caps 64 VGPR (R3/R5/R6); (512,2) -> caps 128 (R4, which
// had a BIGGER footprint and did NOT spill, FETCH 25.7GB). Empirically the 2nd
// launch_bounds arg acts as blocks/CU in this toolchain (4 blocks x 8 waves = 8 waves/
// SIMD -> 64-reg cap). R5/R6's ~100-reg footprint was forced into 64 regs -> per-iter
// scratch. THIS ROUND: R6 kernel verbatim with __launch_bounds__(512,2): 128-reg cap,
// ~100-110 used, no spill; 2 blocks/CU (LDS 34KB also fits), 16 waves/CU in 2 barrier
// domains = R3's healthy occupancy shape.
// Pipe model/CU at this geometry: MFMA 37us, P-LDS ~25us (halved vs R3), V-L2 ~30us,
// VALU ~13us -> expect better overlap than R3's 92.7.
// P LDS: chunk-major [jc 8][i 64][jo 8], 8KB/buf x 4 bufs (pair jt&1; race-free as R2).
__global__ __launch_bounds__(512, 2) void k_attn(const unsigned short* __restrict__ qT,
                                                 const unsigned short* __restrict__ kT,
                                                 const unsigned short* __restrict__ vB,
                                                 const float* __restrict__ x,
                                                 const float* __restrict__ gate,
                                                 const float* __restrict__ gamma,
                                                 float* __restrict__ out) {
    int b = blockIdx.x & 7;
    int i0 = (blockIdx.x >> 3) << 6;     // 64-i tile
    int t = threadIdx.x;
    int w = __builtin_amdgcn_readfirstlane(t >> 6);   // wave-uniform -> SGPR
    int l = t & 63;
    int quad = l >> 4, ln = l & 15;
    int cg = w >> 1;                     // c-group (0..3): PV c-range AND S j-tile (jsub)
    int ih = w & 1;                      // i-half (0..1): S i-range AND PV i-range
    int c0 = cg * 64;                    // PV c-range: 64 wide

    __shared__ __align__(16) unsigned short p_lds[4][4096];   // 4 bufs, chunk-major, 8KB each
    __shared__ float l_s[4][68];

    const short8 zs = {0, 0, 0, 0, 0, 0, 0, 0};
    const f32x4 zf = {0.f, 0.f, 0.f, 0.f};

    // two persistent Q B-frags: B[k=d=quad*8+kk][n=i], i = i0 + ih*32 + u*16 + ln
    short8 bq[2];
    bq[0] = zs; bq[1] = zs;
    if (quad < 2) {
#pragma unroll
        for (int u = 0; u < 2; ++u)
            bq[u] = *(const short8*)(qT + (((size_t)(b * HWN + i0 + ih * 32 + u * 16 + ln)) << 4) + (quad << 3));
    }

    f32x4 acc[4][2];   // [cs][is]: c = c0+cs*16+quad*4+r, i = ih*32+is*16+ln
#pragma unroll
    for (int cs = 0; cs < 4; ++cs)
#pragma unroll
        for (int is = 0; is < 2; ++is) acc[cs][is] = zf;
    float lsum[2] = {0.f, 0.f};

    const float c1 = 1.44269504f;      // log2(e)
    const float c0e = -11.5415603f;    // -8*log2(e): fixed shift, cancels in p/l

    // uniform (SGPR) bases + loop-invariant per-lane (VGPR) offsets, ushort units
    const unsigned short* kb_u = kT + ((size_t)(b * HWN)) * RR;
    const int kln = ((cg * 16 + ln) << 4) + (quad << 3);
    const unsigned short* vb_u = vB + (((size_t)b) << 20) + ((size_t)c0 << 3);
    int vln[8];
#pragma unroll
    for (int ks = 0; ks < 2; ++ks)
#pragma unroll
        for (int cs = 0; cs < 4; ++cs)
            vln[ks * 4 + cs] = (((ks * 4 + quad) << 8) + cs * 16 + ln) << 3;

    // P LDS offsets (ushort units), layout offset(i,j) = ((j>>3)*64 + i)*8 + (j&7)
    // store: j = cg*16 + quad*4 + r, i = ih*32 + u*16 + ln  -> soff + u*128
    int soff = ((cg * 2 + (quad >> 1)) * 64 + ih * 32 + ln) * 8 + (quad & 1) * 4;
    // read: jc = ks*4 + quad, i = ih*32 + is*16 + ln  -> rbase + ks*2048 + is*128
    int rbase = quad * 512 + (ih * 32 + ln) * 8;

    short8 akA = zs, akB = zs;          // K A-frags: chunk0 / chunk1 of current superstep
    short8 av[8];                        // SINGLE V A-frag buffer, [ks*4+cs]

    auto load_ak = [&](short8& ak, int j0) {
        if (quad < 2) ak = *(const short8*)(kb_u + ((j0 << 4) + kln));
    };
    // refill one ks-half of av for chunk at j0
    auto load_av_half = [&](int ks, int j0) {
        const unsigned short* vp = vb_u + (j0 << 8);   // scalar advance
#pragma unroll
        for (int cs = 0; cs < 4; ++cs) av[ks * 4 + cs] = *(const short8*)(vp + vln[ks * 4 + cs]);
    };

    load_ak(akA, 0);
    load_ak(akB, 64);
    load_av_half(0, 0);
    load_av_half(1, 0);

    // exp + pack + store one S^T tile (chunk pbuf, i-subtile u)
    auto finish_s = [&](const f32x4& sf, unsigned short* pbuf, int u) {
        float p0 = exp2f(fmaf(sf[0], c1, c0e));
        float p1 = exp2f(fmaf(sf[1], c1, c0e));
        float p2 = exp2f(fmaf(sf[2], c1, c0e));
        float p3 = exp2f(fmaf(sf[3], c1, c0e));
        lsum[u] += (p0 + p1) + (p2 + p3);
        uint2 pk;
        asm("v_cvt_pk_bf16_f32 %0, %1, %2" : "=v"(pk.x) : "v"(p0), "v"(p1));
        asm("v_cvt_pk_bf16_f32 %0, %1, %2" : "=v"(pk.y) : "v"(p2), "v"(p3));
        *(uint2*)(pbuf + soff + u * 128) = pk;
    };

    // PV over one ks-half of one 64-j chunk: 2 b128 P reads + 8 MFMAs (c 64 x i 32)
    auto pv_ks = [&](int ks, const unsigned short* pbuf) {
        short8 bp[2];
#pragma unroll
        for (int is = 0; is < 2; ++is)
            bp[is] = *(const short8*)(pbuf + rbase + ks * 2048 + is * 128);
#pragma unroll
        for (int cs = 0; cs < 4; ++cs)
#pragma unroll
            for (int is = 0; is < 2; ++is)
                acc[cs][is] = __builtin_amdgcn_mfma_f32_16x16x32_bf16(av[ks * 4 + cs], bp[is], acc[cs][is], 0, 0, 0);
    };

    for (int jt = 0; jt < 32; ++jt) {
        int j0 = jt << 7;
        unsigned short* pb0 = &p_lds[(jt & 1) * 2 + 0][0];
        unsigned short* pb1 = &p_lds[(jt & 1) * 2 + 1][0];

        // ---- QK both chunks x 2 i-subtiles (consumes akA/akB), P stores ----
        f32x4 sA[2], sB[2];
#pragma unroll
        for (int u = 0; u < 2; ++u)
            sA[u] = __builtin_amdgcn_mfma_f32_16x16x32_bf16(akA, bq[u], zf, 0, 0, 0);
#pragma unroll
        for (int u = 0; u < 2; ++u)
            sB[u] = __builtin_amdgcn_mfma_f32_16x16x32_bf16(akB, bq[u], zf, 0, 0, 0);
#pragma unroll
        for (int u = 0; u < 2; ++u) finish_s(sA[u], pb0, u);
#pragma unroll
        for (int u = 0; u < 2; ++u) finish_s(sB[u], pb1, u);

        __syncthreads();   // ONE barrier per 128 j: P pair visible; prev prefetches drained

        bool pf = jt < 31;
        int j0n = j0 + 128;
        // K prefetch for next superstep (akA/akB free after QK above)
        if (pf) { load_ak(akA, j0n); load_ak(akB, j0n + 64); }

        // PV rolling half-refill: consume av half -> refill it for the next chunk;
        // the next 8 MFMAs (+ K prefetch issue) hide each refill's L1/L2 latency.
        pv_ks(0, pb0);
        load_av_half(0, j0 + 64);        // chunk1 ks=0 (always valid: j0+64 <= 4032)
        pv_ks(1, pb0);
        load_av_half(1, j0 + 64);        // chunk1 ks=1
        pv_ks(0, pb1);
        if (pf) load_av_half(0, j0n);    // next superstep chunk0 ks=0
        pv_ks(1, pb1);
        if (pf) load_av_half(1, j0n);    // next superstep chunk0 ks=1
    }

    // l reduction: lane's lsum[u] covers its 4 j's (tile cg) at i = ih*32 + u*16 + ln
#pragma unroll
    for (int u = 0; u < 2; ++u) {
        lsum[u] += __shfl_xor(lsum[u], 16, 64);
        lsum[u] += __shfl_xor(lsum[u], 32, 64);
    }
    if (l < 16) {
#pragma unroll
        for (int u = 0; u < 2; ++u)
            l_s[cg][ih * 32 + u * 16 + l] = lsum[u];
    }
    __syncthreads();

    float g = gamma[0];
    float rinv[2];
#pragma unroll
    for (int is = 0; is < 2; ++is) {
        int i = ih * 32 + is * 16 + ln;
        float lf = (l_s[0][i] + l_s[1][i]) + (l_s[2][i] + l_s[3][i]);
        rinv[is] = g / lf;
    }

    // epilogue: out = gamma*o/l + x*gate
#pragma unroll
    for (int cs = 0; cs < 4; ++cs) {
#pragma unroll
        for (int r = 0; r < 4; ++r) {
            int c = c0 + cs * 16 + quad * 4 + r;
            float gc = gate[b * CCH + c];
            size_t rowoff = (((size_t)(b * CCH + c)) << 12) + i0;
            float* po = out + rowoff;
            const float* px = x + rowoff;
#pragma unroll
            for (int is = 0; is < 2; ++is) {
                int idx = ih * 32 + is * 16 + ln;
                po[idx] = acc[cs][is][r] * rinv[is] + px[idx] * gc;
            }
        }
    }
}

extern "C" void kernel_launch(void* const* d_in, const int* in_sizes, int n_in,
                              void* d_out, int out_size, void* d_ws, size_t ws_size,
                              hipStream_t stream) {
    const float* x = (const float*)d_in[0];
    const float* w1 = (const float*)d_in[1];
    const float* w2 = (const float*)d_in[2];
    const float* qw = (const float*)d_in[3];
    const float* qb = (const float*)d_in[4];
    const float* kw = (const float*)d_in[5];
    const float* kb = (const float*)d_in[6];
    const float* vw = (const float*)d_in[7];
    const float* vb = (const float*)d_in[8];
    const float* gamma = (const float*)d_in[9];
    float* out = (float*)d_out;
    char* ws = (char*)d_ws;

    float* avgp = (float*)(ws);                        // 8 KB
    float* maxp = (float*)(ws + 8192);                 // 8 KB
    float* gate = (float*)(ws + 16384);                // 8 KB
    unsigned short* Wb = (unsigned short*)(ws + 24576);               // [288][256] bf16
    unsigned short* qT = (unsigned short*)(ws + 24576 + 147456);      // 1 MB [b][n][16]
    unsigned short* kT = (unsigned short*)(ws + 24576 + 147456 + 1048576);
    unsigned short* vB = (unsigned short*)(ws + 24576 + 147456 + 2097152);  // 16.8 MB chunked

    k_pool<<<2048, 256, 0, stream>>>(x, avgp, maxp, vw, qw, kw, Wb);  // + fused wprep
    k_gate<<<8, 256, 0, stream>>>(avgp, maxp, w1, w2, gate);
    k_proj<<<512, 256, 0, stream>>>(x, gate, Wb, vb, qb, kb, qT, kT, vB);
    k_attn<<<512, 512, 0, stream>>>(qT, kT, vB, x, gate, gamma, out);
}

// Round 9
// 241.750 us; speedup vs baseline: 1.7581x; 1.1761x over previous
//
#include <hip/hip_runtime.h>
#include <hip/hip_bf16.h>
#include <math.h>

#define BB 8
#define CCH 256
#define HWN 4096
#define RR 16

typedef __attribute__((ext_vector_type(8))) short short8;   // 8 bf16 = K=32 MFMA A/B frag (4 VGPRs)
typedef __attribute__((ext_vector_type(4))) float f32x4;    // MFMA C/D frag

static __device__ __forceinline__ unsigned short f2bf(float x) {
    union { float f; unsigned u; } v; v.f = x;
    return (unsigned short)((v.u + 0x8000u) >> 16);   // round-half-up bf16
}

// ---------------- K1: avg+max pool per (b,c); blocks 0..287 also pack Wb (fused wprep) ----
__global__ __launch_bounds__(256) void k_pool(const float* __restrict__ x,
                                              float* __restrict__ avgp,
                                              float* __restrict__ maxp,
                                              const float* __restrict__ vw,
                                              const float* __restrict__ qw,
                                              const float* __restrict__ kw,
                                              unsigned short* __restrict__ Wb) {
    int bc = blockIdx.x;
    int t = threadIdx.x;
    if (bc < 288) {
        int idx = bc * 256 + t;
        int m = idx >> 8, c = idx & 255;
        float v;
        if (m < 256) v = vw[idx];
        else if (m < 272) v = qw[(m - 256) * 256 + c];
        else v = kw[(m - 272) * 256 + c];
        Wb[idx] = f2bf(v);
    }
    const float4* p = (const float4*)(x + (size_t)bc * HWN);
    float s = 0.f, m = -INFINITY;
#pragma unroll
    for (int i = 0; i < 4; ++i) {
        float4 v = p[t + 256 * i];
        s += v.x + v.y + v.z + v.w;
        m = fmaxf(m, fmaxf(fmaxf(v.x, v.y), fmaxf(v.z, v.w)));
    }
    for (int off = 32; off; off >>= 1) {
        s += __shfl_down(s, off);
        m = fmaxf(m, __shfl_down(m, off));
    }
    __shared__ float ss[4], sm[4];
    int wid = t >> 6;
    if ((t & 63) == 0) { ss[wid] = s; sm[wid] = m; }
    __syncthreads();
    if (t == 0) {
        float S = ss[0] + ss[1] + ss[2] + ss[3];
        float M = fmaxf(fmaxf(sm[0], sm[1]), fmaxf(sm[2], sm[3]));
        avgp[bc] = S * (1.f / (float)HWN);
        maxp[bc] = M;
    }
}

// ---------------- K2: SE gate ----------------
__global__ __launch_bounds__(256) void k_gate(const float* __restrict__ avgp,
                                              const float* __restrict__ maxp,
                                              const float* __restrict__ w1,
                                              const float* __restrict__ w2,
                                              float* __restrict__ gate) {
    int b = blockIdx.x, t = threadIdx.x;
    __shared__ float sa[CCH], sx[CCH], sh[32];
    sa[t] = avgp[b * CCH + t];
    sx[t] = maxp[b * CCH + t];
    __syncthreads();
    if (t < 32) {
        int r = t & 15;
        const float* src = (t < 16) ? sa : sx;
        float h = 0.f;
        for (int c = 0; c < CCH; ++c) h += w1[r * CCH + c] * src[c];
        sh[t] = fmaxf(h, 0.f);
    }
    __syncthreads();
    float g = 0.f;
#pragma unroll
    for (int r = 0; r < RR; ++r) g += w2[t * RR + r] * (sh[r] + sh[16 + r]);
    gate[b * CCH + t] = 1.f / (1.f + __expf(-g));
}

// ---------------- K-proj: fused q,k,v projections — OCCUPANCY + PREFETCH rework ---------
// (R8's k_proj rework, re-audited; R8's failure was in k_attn, not here.)
//   1. vtile HALVED to [128][72] (18.4KB), V streamed in two half-passes (m 0..127 then
//      128..255): LDS 36KB -> 4 blocks/CU, 16 waves/CU, 2 barrier domains.
//   2. x-prefetch (T14): next cc's 4 float4 loaded into regs right after the post-stage
//      barrier, consumed at next loop top -> HBM latency hides under the 36-MFMA phase.
//   3. __launch_bounds__(256,4): empirical VGPR cap 128 ((512,4)->64, (512,2)->128
//      pattern); footprint ~116, no spill.
// Coverage proof: half-pass h writes rows m=h*128..h*128+127 to vtile[(m-h*128)][*];
// read: thread t -> (ch = t&127, Qh = (t>>7)*4), loops Q=Qh..Qh+3 => (c=h*128+ch) x
// (Q 0..7) covered exactly once per pass; write->sync->read in both passes.
__global__ __launch_bounds__(256, 4) void k_proj(const float* __restrict__ x,
                                                 const float* __restrict__ gate,
                                                 const unsigned short* __restrict__ Wb,
                                                 const float* __restrict__ vb,
                                                 const float* __restrict__ qb,
                                                 const float* __restrict__ kb,
                                                 unsigned short* __restrict__ qT,
                                                 unsigned short* __restrict__ kT,
                                                 unsigned short* __restrict__ vB) {
    int b = blockIdx.x & 7;              // XCD swizzle: batch <-> XCD
    int n0 = (blockIdx.x >> 3) << 6;
    int t = threadIdx.x;
    int w = t >> 6, l = t & 63, quad = l >> 4, ln = l & 15;

    __shared__ __align__(16) unsigned short xs_t[64][72];    // [n_local][c_local] bf16, 9.2KB
    __shared__ __align__(16) unsigned short vtile[128 * 72]; // HALF m-range, 18.4KB
    __shared__ float qk_s[32][66];   // q rows 0..15, k rows 16..31 (fp32), 8.4KB

    const f32x4 zf = {0.f, 0.f, 0.f, 0.f};
    f32x4 acc[18];
#pragma unroll
    for (int mt = 0; mt < 18; ++mt) acc[mt] = zf;

    // per-it invariant source pointers (cc advances by 64 c-rows = 1<<18 floats)
    const float* xp[4];
#pragma unroll
    for (int it = 0; it < 4; ++it) {
        int idx = it * 256 + t;
        int cl = idx >> 4, nq = idx & 15;
        xp[it] = x + (((size_t)(b * CCH + cl)) << 12) + n0 + nq * 4;
    }
    float4 xr[4];
#pragma unroll
    for (int it = 0; it < 4; ++it) xr[it] = *(const float4*)xp[it];   // prefetch cc=0

    for (int cc = 0; cc < 4; ++cc) {
        __syncthreads();   // xs_t readers from previous cc done
#pragma unroll
        for (int it = 0; it < 4; ++it) {
            int idx = it * 256 + t;
            int cl = idx >> 4, nq = idx & 15;
            int c = cc * 64 + cl;
            float g = gate[b * CCH + c];
            float4 v = xr[it];
            xs_t[nq * 4 + 0][cl] = f2bf(v.x * g);
            xs_t[nq * 4 + 1][cl] = f2bf(v.y * g);
            xs_t[nq * 4 + 2][cl] = f2bf(v.z * g);
            xs_t[nq * 4 + 3][cl] = f2bf(v.w * g);
        }
        __syncthreads();

        // prefetch next cc's x tile: consumed at next loop top, hidden under MFMA phase
        if (cc < 3) {
#pragma unroll
            for (int it = 0; it < 4; ++it)
                xr[it] = *(const float4*)(xp[it] + (((size_t)(cc + 1)) << 18));
        }

        short8 bfrag[2];
#pragma unroll
        for (int kc = 0; kc < 2; ++kc)
            bfrag[kc] = *(const short8*)&xs_t[w * 16 + ln][kc * 32 + quad * 8];

#pragma unroll
        for (int mt = 0; mt < 18; ++mt) {
#pragma unroll
            for (int kc = 0; kc < 2; ++kc) {
                short8 af = *(const short8*)(Wb + ((size_t)(mt * 16 + ln)) * 256 + cc * 64 + kc * 32 + quad * 8);
                acc[mt] = __builtin_amdgcn_mfma_f32_16x16x32_bf16(af, bfrag[kc], acc[mt], 0, 0, 0);
            }
        }
    }

    unsigned short* vBp = vB + (((size_t)b) << 20);
    int ch = t & 127, Qh = (t >> 7) * 4;

    // ---- V half-pass 0: m = 0..127 ----
#pragma unroll
    for (int mt = 0; mt < 8; ++mt) {
#pragma unroll
        for (int r = 0; r < 4; ++r) {
            int m = mt * 16 + quad * 4 + r;
            vtile[m * 72 + w * 16 + ln] = f2bf(acc[mt][r] + vb[m]);
        }
    }
    // q/k -> LDS for transpose (once)
#pragma unroll
    for (int r = 0; r < 4; ++r) {
        qk_s[quad * 4 + r][w * 16 + ln] = acc[16][r];
        qk_s[16 + quad * 4 + r][w * 16 + ln] = acc[17][r];
    }
    __syncthreads();
#pragma unroll
    for (int qq = 0; qq < 4; ++qq) {
        int Q = Qh + qq;
        short8 v8 = *(const short8*)(vtile + ch * 72 + Q * 8);
        *(short8*)(vBp + ((size_t)((((n0 >> 3) + Q) << 8) + ch) << 3)) = v8;
    }
    __syncthreads();

    // ---- V half-pass 1: m = 128..255 ----
#pragma unroll
    for (int mt = 8; mt < 16; ++mt) {
#pragma unroll
        for (int r = 0; r < 4; ++r) {
            int m = mt * 16 + quad * 4 + r;
            vtile[(m - 128) * 72 + w * 16 + ln] = f2bf(acc[mt][r] + vb[m]);
        }
    }
    __syncthreads();
#pragma unroll
    for (int qq = 0; qq < 4; ++qq) {
        int Q = Qh + qq;
        short8 v8 = *(const short8*)(vtile + ch * 72 + Q * 8);
        *(short8*)(vBp + ((size_t)((((n0 >> 3) + Q) << 8) + (128 + ch)) << 3)) = v8;
    }

    if (t < 128) {
        int isK = t >> 6;
        int n = t & 63;
        const float* bias = isK ? kb : qb;
        unsigned u32[8];
#pragma unroll
        for (int j = 0; j < 8; ++j) {
            unsigned lo = f2bf(qk_s[isK * 16 + 2 * j][n] + bias[2 * j]);
            unsigned hi = f2bf(qk_s[isK * 16 + 2 * j + 1][n] + bias[2 * j + 1]);
            u32[j] = lo | (hi << 16);
        }
        unsigned short* dst = (isK ? kT : qT) + ((size_t)(b * HWN + n0 + n)) * RR;
        uint4 d0 = {u32[0], u32[1], u32[2], u32[3]};
        uint4 d1 = {u32[4], u32[5], u32[6], u32[7]};
        ((uint4*)dst)[0] = d0;
        ((uint4*)dst)[1] = d1;
    }
}

// ---------------- K-attn: TRUE R3 champion (92.7us), copied from Round-3 listing --------
// (32c x 64i) waves: acc[2][4] = 32 f32; wave w: PV c-range c0 = w*32 (exclusive),
// PV i-range FULL 64 (is 0..3); S production jsub = w>>1 (j-tile), ih = w&1 (i-half).
// Grid 512, 1 barrier per 128j superstep, V/K register dbuf refilled per superstep.
// R8 bug (now fixed): a re-derived "revert" wrote only each wave's own i-half in the
// epilogue -> half of out unwritten. This version is the logged champion verbatim.
__global__ __launch_bounds__(512, 4) void k_attn(const unsigned short* __restrict__ qT,
                                                 const unsigned short* __restrict__ kT,
                                                 const unsigned short* __restrict__ vB,
                                                 const float* __restrict__ x,
                                                 const float* __restrict__ gate,
                                                 const float* __restrict__ gamma,
                                                 float* __restrict__ out) {
    int b = blockIdx.x & 7;
    int i0 = (blockIdx.x >> 3) << 6;     // 64-i tile
    int t = threadIdx.x;
    int w = __builtin_amdgcn_readfirstlane(t >> 6);   // wave-uniform -> SGPR
    int l = t & 63;
    int quad = l >> 4, ln = l & 15;
    int jsub = w >> 1;                   // S-production j-tile (0..3)
    int ih = w & 1;                      // S-production i-half (0..1)
    int c0 = w * 32;                     // PV c-range: exclusive per wave

    __shared__ __align__(16) unsigned short p_lds[4][4096];   // 4 bufs, chunk-major, 8KB each
    __shared__ float l_s[4][68];

    const short8 zs = {0, 0, 0, 0, 0, 0, 0, 0};
    const f32x4 zf = {0.f, 0.f, 0.f, 0.f};

    // two persistent Q B-frags: B[k=d=quad*8+kk][n=i], i = i0 + ih*32 + u*16 + ln
    short8 bq[2];
    bq[0] = zs; bq[1] = zs;
    if (quad < 2) {
#pragma unroll
        for (int u = 0; u < 2; ++u)
            bq[u] = *(const short8*)(qT + (((size_t)(b * HWN + i0 + ih * 32 + u * 16 + ln)) << 4) + (quad << 3));
    }

    f32x4 acc[2][4];   // [cs][is]: c = c0+cs*16+quad*4+r, i = is*16+ln
#pragma unroll
    for (int cs = 0; cs < 2; ++cs)
#pragma unroll
        for (int is = 0; is < 4; ++is) acc[cs][is] = zf;
    float lsum[2] = {0.f, 0.f};

    const float c1 = 1.44269504f;      // log2(e)
    const float c0e = -11.5415603f;    // -8*log2(e): fixed shift, cancels in p/l

    // uniform (SGPR) bases + loop-invariant per-lane (VGPR) offsets, ushort units
    const unsigned short* kb_u = kT + ((size_t)(b * HWN)) * RR;
    const int kln = ((jsub * 16 + ln) << 4) + (quad << 3);
    const unsigned short* vb_u = vB + (((size_t)b) << 20) + ((size_t)c0 << 3);
    int vln[4];
#pragma unroll
    for (int ks = 0; ks < 2; ++ks)
#pragma unroll
        for (int cs = 0; cs < 2; ++cs)
            vln[ks * 2 + cs] = (((ks * 4 + quad) << 8) + cs * 16 + ln) << 3;

    // P LDS offsets (ushort units), layout offset(i,j) = ((j>>3)*64 + i)*8 + (j&7)
    // store: j = jsub*16 + quad*4 + r, i = ih*32 + u*16 + ln  -> soff + u*128
    int soff = ((jsub * 2 + (quad >> 1)) * 64 + ih * 32 + ln) * 8 + (quad & 1) * 4;
    // read: jc = ks*4 + quad, i = is*16 + ln  -> rbase + ks*2048 + is*128
    int rbase = quad * 512 + ln * 8;

    short8 akA = zs, akB = zs;          // K A-frags: chunk0 / chunk1 of current superstep
    short8 avA[4], avB[4];              // V A-frags: chunk0 / chunk1, [ks*2+cs]

    auto load_ak = [&](short8& ak, int j0) {
        if (quad < 2) ak = *(const short8*)(kb_u + ((j0 << 4) + kln));
    };
    auto load_av = [&](short8 (&av)[4], int j0) {
        const unsigned short* vp = vb_u + (j0 << 8);   // scalar advance
#pragma unroll
        for (int u = 0; u < 4; ++u) av[u] = *(const short8*)(vp + vln[u]);
    };

    load_ak(akA, 0);
    load_ak(akB, 64);
    load_av(avA, 0);
    load_av(avB, 64);

    // exp + pack + store one S^T tile (chunk pbuf, i-subtile u)
    auto finish_s = [&](const f32x4& sf, unsigned short* pbuf, int u) {
        float p0 = exp2f(fmaf(sf[0], c1, c0e));
        float p1 = exp2f(fmaf(sf[1], c1, c0e));
        float p2 = exp2f(fmaf(sf[2], c1, c0e));
        float p3 = exp2f(fmaf(sf[3], c1, c0e));
        lsum[u] += (p0 + p1) + (p2 + p3);
        uint2 pk;
        asm("v_cvt_pk_bf16_f32 %0, %1, %2" : "=v"(pk.x) : "v"(p0), "v"(p1));
        asm("v_cvt_pk_bf16_f32 %0, %1, %2" : "=v"(pk.y) : "v"(p2), "v"(p3));
        *(uint2*)(pbuf + soff + u * 128) = pk;
    };

    // PV over one 64-j chunk: 8 b128 P reads + 16 MFMAs (c 32 x i 64)
    auto pv = [&](const short8 (&av)[4], const unsigned short* pbuf) {
#pragma unroll
        for (int ks = 0; ks < 2; ++ks) {
            short8 bp[4];
#pragma unroll
            for (int is = 0; is < 4; ++is)
                bp[is] = *(const short8*)(pbuf + rbase + ks * 2048 + is * 128);
#pragma unroll
            for (int cs = 0; cs < 2; ++cs)
#pragma unroll
                for (int is = 0; is < 4; ++is)
                    acc[cs][is] = __builtin_amdgcn_mfma_f32_16x16x32_bf16(av[ks * 2 + cs], bp[is], acc[cs][is], 0, 0, 0);
        }
    };

    for (int jt = 0; jt < 32; ++jt) {
        unsigned short* pb0 = &p_lds[(jt & 1) * 2 + 0][0];
        unsigned short* pb1 = &p_lds[(jt & 1) * 2 + 1][0];

        // ---- QK both chunks x both i-subtiles (consumes akA/akB), P stores ----
        f32x4 sf00 = __builtin_amdgcn_mfma_f32_16x16x32_bf16(akA, bq[0], zf, 0, 0, 0);
        f32x4 sf01 = __builtin_amdgcn_mfma_f32_16x16x32_bf16(akA, bq[1], zf, 0, 0, 0);
        f32x4 sf10 = __builtin_amdgcn_mfma_f32_16x16x32_bf16(akB, bq[0], zf, 0, 0, 0);
        f32x4 sf11 = __builtin_amdgcn_mfma_f32_16x16x32_bf16(akB, bq[1], zf, 0, 0, 0);
        finish_s(sf00, pb0, 0);
        finish_s(sf01, pb0, 1);
        finish_s(sf10, pb1, 0);
        finish_s(sf11, pb1, 1);

        __syncthreads();   // ONE barrier per 128 j: P pair visible; prev prefetches drained

        bool pf = jt < 31;
        int j0n = (jt + 1) << 7;
        // K prefetch for next superstep (akA/akB free after QK above)
        if (pf) { load_ak(akA, j0n); load_ak(akB, j0n + 64); }

        // PV chunk0 (consumes avA) then refill avA; PV chunk1 then refill avB
        pv(avA, pb0);
        if (pf) load_av(avA, j0n);
        pv(avB, pb1);
        if (pf) load_av(avB, j0n + 64);
    }

    // l reduction: lane's lsum[u] covers its 4 j's for i = ih*32 + u*16 + ln
    lsum[0] += __shfl_xor(lsum[0], 16, 64);
    lsum[0] += __shfl_xor(lsum[0], 32, 64);
    lsum[1] += __shfl_xor(lsum[1], 16, 64);
    lsum[1] += __shfl_xor(lsum[1], 32, 64);
    if (l < 16) {
        l_s[jsub][ih * 32 + l] = lsum[0];
        l_s[jsub][ih * 32 + 16 + l] = lsum[1];
    }
    __syncthreads();

    float g = gamma[0];
    float rinv[4];
#pragma unroll
    for (int is = 0; is < 4; ++is) {
        int i = is * 16 + ln;
        float lf = (l_s[0][i] + l_s[1][i]) + (l_s[2][i] + l_s[3][i]);
        rinv[is] = g / lf;
    }

    // epilogue: out = gamma*o/l + x*gate
#pragma unroll
    for (int cs = 0; cs < 2; ++cs) {
#pragma unroll
        for (int r = 0; r < 4; ++r) {
            int c = c0 + cs * 16 + quad * 4 + r;
            float gc = gate[b * CCH + c];
            size_t rowoff = (((size_t)(b * CCH + c)) << 12) + i0;
            float* po = out + rowoff;
            const float* px = x + rowoff;
#pragma unroll
            for (int is = 0; is < 4; ++is) {
                int idx = is * 16 + ln;
                po[idx] = acc[cs][is][r] * rinv[is] + px[idx] * gc;
            }
        }
    }
}

extern "C" void kernel_launch(void* const* d_in, const int* in_sizes, int n_in,
                              void* d_out, int out_size, void* d_ws, size_t ws_size,
                              hipStream_t stream) {
    const float* x = (const float*)d_in[0];
    const float* w1 = (const float*)d_in[1];
    const float* w2 = (const float*)d_in[2];
    const float* qw = (const float*)d_in[3];
    const float* qb = (const float*)d_in[4];
    const float* kw = (const float*)d_in[5];
    const float* kb = (const float*)d_in[6];
    const float* vw = (const float*)d_in[7];
    const float* vb = (const float*)d_in[8];
    const float* gamma = (const float*)d_in[9];
    float* out = (float*)d_out;
    char* ws = (char*)d_ws;

    float* avgp = (float*)(ws);                        // 8 KB
    float* maxp = (float*)(ws + 8192);                 // 8 KB
    float* gate = (float*)(ws + 16384);                // 8 KB
    unsigned short* Wb = (unsigned short*)(ws + 24576);               // [288][256] bf16
    unsigned short* qT = (unsigned short*)(ws + 24576 + 147456);      // 1 MB [b][n][16]
    unsigned short* kT = (unsigned short*)(ws + 24576 + 147456 + 1048576);
    unsigned short* vB = (unsigned short*)(ws + 24576 + 147456 + 2097152);  // 16.8 MB chunked

    k_pool<<<2048, 256, 0, stream>>>(x, avgp, maxp, vw, qw, kw, Wb);  // + fused wprep
    k_gate<<<8, 256, 0, stream>>>(avgp, maxp, w1, w2, gate);
    k_proj<<<512, 256, 0, stream>>>(x, gate, Wb, vb, qb, kb, qT, kT, vB);
    k_attn<<<512, 512, 0, stream>>>(qT, kT, vB, x, gate, gamma, out);
}

// Round 10
// 222.609 us; speedup vs baseline: 1.9093x; 1.0860x over previous
//
#include <hip/hip_runtime.h>
#include <hip/hip_bf16.h>
#include <math.h>

#define BB 8
#define CCH 256
#define HWN 4096
#define RR 16

typedef __attribute__((ext_vector_type(8))) short short8;   // 8 bf16 = K=32 MFMA A/B frag (4 VGPRs)
typedef __attribute__((ext_vector_type(4))) float f32x4;    // MFMA C/D frag

static __device__ __forceinline__ unsigned short f2bf(float x) {
    union { float f; unsigned u; } v; v.f = x;
    return (unsigned short)((v.u + 0x8000u) >> 16);   // round-half-up bf16
}

// ---------------- K1: avg+max pool per (b,c); blocks 0..287 also pack Wb (fused wprep) ----
__global__ __launch_bounds__(256) void k_pool(const float* __restrict__ x,
                                              float* __restrict__ avgp,
                                              float* __restrict__ maxp,
                                              const float* __restrict__ vw,
                                              const float* __restrict__ qw,
                                              const float* __restrict__ kw,
                                              unsigned short* __restrict__ Wb) {
    int bc = blockIdx.x;
    int t = threadIdx.x;
    if (bc < 288) {
        int idx = bc * 256 + t;
        int m = idx >> 8, c = idx & 255;
        float v;
        if (m < 256) v = vw[idx];
        else if (m < 272) v = qw[(m - 256) * 256 + c];
        else v = kw[(m - 272) * 256 + c];
        Wb[idx] = f2bf(v);
    }
    const float4* p = (const float4*)(x + (size_t)bc * HWN);
    float s = 0.f, m = -INFINITY;
#pragma unroll
    for (int i = 0; i < 4; ++i) {
        float4 v = p[t + 256 * i];
        s += v.x + v.y + v.z + v.w;
        m = fmaxf(m, fmaxf(fmaxf(v.x, v.y), fmaxf(v.z, v.w)));
    }
    for (int off = 32; off; off >>= 1) {
        s += __shfl_down(s, off);
        m = fmaxf(m, __shfl_down(m, off));
    }
    __shared__ float ss[4], sm[4];
    int wid = t >> 6;
    if ((t & 63) == 0) { ss[wid] = s; sm[wid] = m; }
    __syncthreads();
    if (t == 0) {
        float S = ss[0] + ss[1] + ss[2] + ss[3];
        float M = fmaxf(fmaxf(sm[0], sm[1]), fmaxf(sm[2], sm[3]));
        avgp[bc] = S * (1.f / (float)HWN);
        maxp[bc] = M;
    }
}

// ---------------- K2: SE gate ----------------
__global__ __launch_bounds__(256) void k_gate(const float* __restrict__ avgp,
                                              const float* __restrict__ maxp,
                                              const float* __restrict__ w1,
                                              const float* __restrict__ w2,
                                              float* __restrict__ gate) {
    int b = blockIdx.x, t = threadIdx.x;
    __shared__ float sa[CCH], sx[CCH], sh[32];
    sa[t] = avgp[b * CCH + t];
    sx[t] = maxp[b * CCH + t];
    __syncthreads();
    if (t < 32) {
        int r = t & 15;
        const float* src = (t < 16) ? sa : sx;
        float h = 0.f;
        for (int c = 0; c < CCH; ++c) h += w1[r * CCH + c] * src[c];
        sh[t] = fmaxf(h, 0.f);
    }
    __syncthreads();
    float g = 0.f;
#pragma unroll
    for (int r = 0; r < RR; ++r) g += w2[t * RR + r] * (sh[r] + sh[16 + r]);
    gate[b * CCH + t] = 1.f / (1.f + __expf(-g));
}

// ---------------- K-proj: ORIGINAL structure (R0-R7, residue ~134) + x-prefetch ONLY ----
// R9 post-mortem: the full rework (vtile half-pass + (256,4) cap 128 vs ~125 footprint)
// regressed residue 134->148. Decomposed: keep ONLY the register x-prefetch (T14,
// indexing verified correct by R9's passing run); revert structure + launch bounds
// (no min-waves arg -> 256-VGPR cap, zero spill risk; acc72+xr16 ~ 130 regs fits).
// Mechanism: at 2 waves/SIMD (LDS 54.5KB -> 2 blocks/CU) there is no TLP to hide the
// per-cc HBM x-load latency; issuing the loads during the previous cc's 36-MFMA phase
// hides ~900 cyc x 4 ccs.
__global__ __launch_bounds__(256) void k_proj(const float* __restrict__ x,
                                              const float* __restrict__ gate,
                                              const unsigned short* __restrict__ Wb,
                                              const float* __restrict__ vb,
                                              const float* __restrict__ qb,
                                              const float* __restrict__ kb,
                                              unsigned short* __restrict__ qT,
                                              unsigned short* __restrict__ kT,
                                              unsigned short* __restrict__ vB) {
    int b = blockIdx.x & 7;              // XCD swizzle: batch <-> XCD
    int n0 = (blockIdx.x >> 3) << 6;
    int t = threadIdx.x;
    int w = t >> 6, l = t & 63, quad = l >> 4, ln = l & 15;

    __shared__ __align__(16) unsigned short xs_t[64][72];    // [n_local][c_local] bf16
    __shared__ __align__(16) unsigned short vtile[256 * 72]; // [m][n_local] bf16, stride 72
    __shared__ float qk_s[32][66];   // q rows 0..15, k rows 16..31 (fp32)

    const f32x4 zf = {0.f, 0.f, 0.f, 0.f};
    f32x4 acc[18];
#pragma unroll
    for (int mt = 0; mt < 18; ++mt) acc[mt] = zf;

    // per-it invariant source pointers (cc advances by 64 c-rows = 1<<18 floats)
    const float* xp[4];
#pragma unroll
    for (int it = 0; it < 4; ++it) {
        int idx = it * 256 + t;
        int cl = idx >> 4, nq = idx & 15;
        xp[it] = x + (((size_t)(b * CCH + cl)) << 12) + n0 + nq * 4;
    }
    float4 xr[4];
#pragma unroll
    for (int it = 0; it < 4; ++it) xr[it] = *(const float4*)xp[it];   // prefetch cc=0

    for (int cc = 0; cc < 4; ++cc) {
        __syncthreads();
#pragma unroll
        for (int it = 0; it < 4; ++it) {
            int idx = it * 256 + t;
            int cl = idx >> 4, nq = idx & 15;
            int c = cc * 64 + cl;
            float g = gate[b * CCH + c];
            float4 v = xr[it];
            xs_t[nq * 4 + 0][cl] = f2bf(v.x * g);
            xs_t[nq * 4 + 1][cl] = f2bf(v.y * g);
            xs_t[nq * 4 + 2][cl] = f2bf(v.z * g);
            xs_t[nq * 4 + 3][cl] = f2bf(v.w * g);
        }
        __syncthreads();

        // prefetch next cc's x tile: consumed at next loop top, hidden under MFMA phase
        if (cc < 3) {
#pragma unroll
            for (int it = 0; it < 4; ++it)
                xr[it] = *(const float4*)(xp[it] + (((size_t)(cc + 1)) << 18));
        }

        short8 bfrag[2];
#pragma unroll
        for (int kc = 0; kc < 2; ++kc)
            bfrag[kc] = *(const short8*)&xs_t[w * 16 + ln][kc * 32 + quad * 8];

#pragma unroll
        for (int mt = 0; mt < 18; ++mt) {
#pragma unroll
            for (int kc = 0; kc < 2; ++kc) {
                short8 af = *(const short8*)(Wb + ((size_t)(mt * 16 + ln)) * 256 + cc * 64 + kc * 32 + quad * 8);
                acc[mt] = __builtin_amdgcn_mfma_f32_16x16x32_bf16(af, bfrag[kc], acc[mt], 0, 0, 0);
            }
        }
    }

    // v rows -> vtile[m][n_local]
#pragma unroll
    for (int mt = 0; mt < 16; ++mt) {
#pragma unroll
        for (int r = 0; r < 4; ++r) {
            int m = mt * 16 + quad * 4 + r;
            vtile[m * 72 + w * 16 + ln] = f2bf(acc[mt][r] + vb[m]);
        }
    }
    // q/k -> LDS for transpose
#pragma unroll
    for (int r = 0; r < 4; ++r) {
        qk_s[quad * 4 + r][w * 16 + ln] = acc[16][r];
        qk_s[16 + quad * 4 + r][w * 16 + ln] = acc[17][r];
    }
    __syncthreads();

    // stream vtile -> vB chunks: thread t = c; 8 x 16B stores, 1KB coalesced segments
    {
        unsigned short* vBp = vB + (((size_t)b) << 20);
        int c = t;
#pragma unroll
        for (int Q = 0; Q < 8; ++Q) {
            short8 v8 = *(const short8*)(vtile + c * 72 + Q * 8);
            *(short8*)(vBp + ((size_t)((((n0 >> 3) + Q) << 8) + c) << 3)) = v8;
        }
    }
    if (t < 128) {
        int isK = t >> 6;
        int n = t & 63;
        const float* bias = isK ? kb : qb;
        unsigned u32[8];
#pragma unroll
        for (int j = 0; j < 8; ++j) {
            unsigned lo = f2bf(qk_s[isK * 16 + 2 * j][n] + bias[2 * j]);
            unsigned hi = f2bf(qk_s[isK * 16 + 2 * j + 1][n] + bias[2 * j + 1]);
            u32[j] = lo | (hi << 16);
        }
        unsigned short* dst = (isK ? kT : qT) + ((size_t)(b * HWN + n0 + n)) * RR;
        uint4 d0 = {u32[0], u32[1], u32[2], u32[3]};
        uint4 d1 = {u32[4], u32[5], u32[6], u32[7]};
        ((uint4*)dst)[0] = d0;
        ((uint4*)dst)[1] = d1;
    }
}

// ---------------- K-attn: TRUE R3 champion — verbatim from R9 (93.5us measured) ---------
// (32c x 64i) waves: acc[2][4] = 32 f32; wave w: PV c-range c0 = w*32 (exclusive),
// PV i-range FULL 64 (is 0..3); S production jsub = w>>1 (j-tile), ih = w&1 (i-half).
// Grid 512, 1 barrier per 128j superstep, V/K register dbuf refilled per superstep.
__global__ __launch_bounds__(512, 4) void k_attn(const unsigned short* __restrict__ qT,
                                                 const unsigned short* __restrict__ kT,
                                                 const unsigned short* __restrict__ vB,
                                                 const float* __restrict__ x,
                                                 const float* __restrict__ gate,
                                                 const float* __restrict__ gamma,
                                                 float* __restrict__ out) {
    int b = blockIdx.x & 7;
    int i0 = (blockIdx.x >> 3) << 6;     // 64-i tile
    int t = threadIdx.x;
    int w = __builtin_amdgcn_readfirstlane(t >> 6);   // wave-uniform -> SGPR
    int l = t & 63;
    int quad = l >> 4, ln = l & 15;
    int jsub = w >> 1;                   // S-production j-tile (0..3)
    int ih = w & 1;                      // S-production i-half (0..1)
    int c0 = w * 32;                     // PV c-range: exclusive per wave

    __shared__ __align__(16) unsigned short p_lds[4][4096];   // 4 bufs, chunk-major, 8KB each
    __shared__ float l_s[4][68];

    const short8 zs = {0, 0, 0, 0, 0, 0, 0, 0};
    const f32x4 zf = {0.f, 0.f, 0.f, 0.f};

    // two persistent Q B-frags: B[k=d=quad*8+kk][n=i], i = i0 + ih*32 + u*16 + ln
    short8 bq[2];
    bq[0] = zs; bq[1] = zs;
    if (quad < 2) {
#pragma unroll
        for (int u = 0; u < 2; ++u)
            bq[u] = *(const short8*)(qT + (((size_t)(b * HWN + i0 + ih * 32 + u * 16 + ln)) << 4) + (quad << 3));
    }

    f32x4 acc[2][4];   // [cs][is]: c = c0+cs*16+quad*4+r, i = is*16+ln
#pragma unroll
    for (int cs = 0; cs < 2; ++cs)
#pragma unroll
        for (int is = 0; is < 4; ++is) acc[cs][is] = zf;
    float lsum[2] = {0.f, 0.f};

    const float c1 = 1.44269504f;      // log2(e)
    const float c0e = -11.5415603f;    // -8*log2(e): fixed shift, cancels in p/l

    // uniform (SGPR) bases + loop-invariant per-lane (VGPR) offsets, ushort units
    const unsigned short* kb_u = kT + ((size_t)(b * HWN)) * RR;
    const int kln = ((jsub * 16 + ln) << 4) + (quad << 3);
    const unsigned short* vb_u = vB + (((size_t)b) << 20) + ((size_t)c0 << 3);
    int vln[4];
#pragma unroll
    for (int ks = 0; ks < 2; ++ks)
#pragma unroll
        for (int cs = 0; cs < 2; ++cs)
            vln[ks * 2 + cs] = (((ks * 4 + quad) << 8) + cs * 16 + ln) << 3;

    // P LDS offsets (ushort units), layout offset(i,j) = ((j>>3)*64 + i)*8 + (j&7)
    // store: j = jsub*16 + quad*4 + r, i = ih*32 + u*16 + ln  -> soff + u*128
    int soff = ((jsub * 2 + (quad >> 1)) * 64 + ih * 32 + ln) * 8 + (quad & 1) * 4;
    // read: jc = ks*4 + quad, i = is*16 + ln  -> rbase + ks*2048 + is*128
    int rbase = quad * 512 + ln * 8;

    short8 akA = zs, akB = zs;          // K A-frags: chunk0 / chunk1 of current superstep
    short8 avA[4], avB[4];              // V A-frags: chunk0 / chunk1, [ks*2+cs]

    auto load_ak = [&](short8& ak, int j0) {
        if (quad < 2) ak = *(const short8*)(kb_u + ((j0 << 4) + kln));
    };
    auto load_av = [&](short8 (&av)[4], int j0) {
        const unsigned short* vp = vb_u + (j0 << 8);   // scalar advance
#pragma unroll
        for (int u = 0; u < 4; ++u) av[u] = *(const short8*)(vp + vln[u]);
    };

    load_ak(akA, 0);
    load_ak(akB, 64);
    load_av(avA, 0);
    load_av(avB, 64);

    // exp + pack + store one S^T tile (chunk pbuf, i-subtile u)
    auto finish_s = [&](const f32x4& sf, unsigned short* pbuf, int u) {
        float p0 = exp2f(fmaf(sf[0], c1, c0e));
        float p1 = exp2f(fmaf(sf[1], c1, c0e));
        float p2 = exp2f(fmaf(sf[2], c1, c0e));
        float p3 = exp2f(fmaf(sf[3], c1, c0e));
        lsum[u] += (p0 + p1) + (p2 + p3);
        uint2 pk;
        asm("v_cvt_pk_bf16_f32 %0, %1, %2" : "=v"(pk.x) : "v"(p0), "v"(p1));
        asm("v_cvt_pk_bf16_f32 %0, %1, %2" : "=v"(pk.y) : "v"(p2), "v"(p3));
        *(uint2*)(pbuf + soff + u * 128) = pk;
    };

    // PV over one 64-j chunk: 8 b128 P reads + 16 MFMAs (c 32 x i 64)
    auto pv = [&](const short8 (&av)[4], const unsigned short* pbuf) {
#pragma unroll
        for (int ks = 0; ks < 2; ++ks) {
            short8 bp[4];
#pragma unroll
            for (int is = 0; is < 4; ++is)
                bp[is] = *(const short8*)(pbuf + rbase + ks * 2048 + is * 128);
#pragma unroll
            for (int cs = 0; cs < 2; ++cs)
#pragma unroll
                for (int is = 0; is < 4; ++is)
                    acc[cs][is] = __builtin_amdgcn_mfma_f32_16x16x32_bf16(av[ks * 2 + cs], bp[is], acc[cs][is], 0, 0, 0);
        }
    };

    for (int jt = 0; jt < 32; ++jt) {
        unsigned short* pb0 = &p_lds[(jt & 1) * 2 + 0][0];
        unsigned short* pb1 = &p_lds[(jt & 1) * 2 + 1][0];

        // ---- QK both chunks x both i-subtiles (consumes akA/akB), P stores ----
        f32x4 sf00 = __builtin_amdgcn_mfma_f32_16x16x32_bf16(akA, bq[0], zf, 0, 0, 0);
        f32x4 sf01 = __builtin_amdgcn_mfma_f32_16x16x32_bf16(akA, bq[1], zf, 0, 0, 0);
        f32x4 sf10 = __builtin_amdgcn_mfma_f32_16x16x32_bf16(akB, bq[0], zf, 0, 0, 0);
        f32x4 sf11 = __builtin_amdgcn_mfma_f32_16x16x32_bf16(akB, bq[1], zf, 0, 0, 0);
        finish_s(sf00, pb0, 0);
        finish_s(sf01, pb0, 1);
        finish_s(sf10, pb1, 0);
        finish_s(sf11, pb1, 1);

        __syncthreads();   // ONE barrier per 128 j: P pair visible; prev prefetches drained

        bool pf = jt < 31;
        int j0n = (jt + 1) << 7;
        // K prefetch for next superstep (akA/akB free after QK above)
        if (pf) { load_ak(akA, j0n); load_ak(akB, j0n + 64); }

        // PV chunk0 (consumes avA) then refill avA; PV chunk1 then refill avB
        pv(avA, pb0);
        if (pf) load_av(avA, j0n);
        pv(avB, pb1);
        if (pf) load_av(avB, j0n + 64);
    }

    // l reduction: lane's lsum[u] covers its 4 j's for i = ih*32 + u*16 + ln
    lsum[0] += __shfl_xor(lsum[0], 16, 64);
    lsum[0] += __shfl_xor(lsum[0], 32, 64);
    lsum[1] += __shfl_xor(lsum[1], 16, 64);
    lsum[1] += __shfl_xor(lsum[1], 32, 64);
    if (l < 16) {
        l_s[jsub][ih * 32 + l] = lsum[0];
        l_s[jsub][ih * 32 + 16 + l] = lsum[1];
    }
    __syncthreads();

    float g = gamma[0];
    float rinv[4];
#pragma unroll
    for (int is = 0; is < 4; ++is) {
        int i = is * 16 + ln;
        float lf = (l_s[0][i] + l_s[1][i]) + (l_s[2][i] + l_s[3][i]);
        rinv[is] = g / lf;
    }

    // epilogue: out = gamma*o/l + x*gate
#pragma unroll
    for (int cs = 0; cs < 2; ++cs) {
#pragma unroll
        for (int r = 0; r < 4; ++r) {
            int c = c0 + cs * 16 + quad * 4 + r;
            float gc = gate[b * CCH + c];
            size_t rowoff = (((size_t)(b * CCH + c)) << 12) + i0;
            float* po = out + rowoff;
            const float* px = x + rowoff;
#pragma unroll
            for (int is = 0; is < 4; ++is) {
                int idx = is * 16 + ln;
                po[idx] = acc[cs][is][r] * rinv[is] + px[idx] * gc;
            }
        }
    }
}

extern "C" void kernel_launch(void* const* d_in, const int* in_sizes, int n_in,
                              void* d_out, int out_size, void* d_ws, size_t ws_size,
                              hipStream_t stream) {
    const float* x = (const float*)d_in[0];
    const float* w1 = (const float*)d_in[1];
    const float* w2 = (const float*)d_in[2];
    const float* qw = (const float*)d_in[3];
    const float* qb = (const float*)d_in[4];
    const float* kw = (const float*)d_in[5];
    const float* kb = (const float*)d_in[6];
    const float* vw = (const float*)d_in[7];
    const float* vb = (const float*)d_in[8];
    const float* gamma = (const float*)d_in[9];
    float* out = (float*)d_out;
    char* ws = (char*)d_ws;

    float* avgp = (float*)(ws);                        // 8 KB
    float* maxp = (float*)(ws + 8192);                 // 8 KB
    float* gate = (float*)(ws + 16384);                // 8 KB
    unsigned short* Wb = (unsigned short*)(ws + 24576);               // [288][256] bf16
    unsigned short* qT = (unsigned short*)(ws + 24576 + 147456);      // 1 MB [b][n][16]
    unsigned short* kT = (unsigned short*)(ws + 24576 + 147456 + 1048576);
    unsigned short* vB = (unsigned short*)(ws + 24576 + 147456 + 2097152);  // 16.8 MB chunked

    k_pool<<<2048, 256, 0, stream>>>(x, avgp, maxp, vw, qw, kw, Wb);  // + fused wprep
    k_gate<<<8, 256, 0, stream>>>(avgp, maxp, w1, w2, gate);
    k_proj<<<512, 256, 0, stream>>>(x, gate, Wb, vb, qb, kb, qT, kT, vB);
    k_attn<<<512, 512, 0, stream>>>(qT, kT, vB, x, gate, gamma, out);
}